// Round 1
// baseline (200.579 us; speedup 1.0000x reference)
//
#include <hip/hip_runtime.h>
#include <hip/hip_bf16.h>
#include <math.h>

#define VOCAB 30522
#define EMBED 768
#define NUM_CAT 18
#define HIS 50
#define SEQ 32
#define BATCH 64
#define CLICK_DIM 100

// ---------------- ws layout (float offsets) ----------------
// [0, 2457600)            pooled   [3200][768]
// [2457600, 4915200)      news_repr[3200][768]
// [4915200, 4918400)      news_w   [3200]
// [4918400, 4919552)      final_logit [64*18]
// [4919552]               mask-layout flag (int)
#define WS_POOLED 0
#define WS_NR     2457600
#define WS_NEWSW  4915200
#define WS_LOGIT  4918400
#define WS_FLAG   4919552

// flag: 0 = int32 mask, 1 = uint8 (np.bool_) mask, 2 = float32 mask
__device__ __forceinline__ bool read_mask(const void* p, int i, int flag) {
    if (flag == 0) return ((const int*)p)[i] != 0;
    if (flag == 1) return ((const unsigned char*)p)[i] != 0;
    return ((const float*)p)[i] != 0.0f;
}

// ---------------- K0: detect bool layout from category_mask ----------------
__global__ void k0_detect(const unsigned int* __restrict__ cm, int* flag_out) {
    // 57600 elements. First 14400 words are valid under BOTH u8 (57600B) and
    // i32 (230400B) layouts.
    __shared__ int word_gt1, byte_gt1;
    if (threadIdx.x == 0) { word_gt1 = 0; byte_gt1 = 0; }
    __syncthreads();
    int lw = 0, lb = 0;
    for (int i = threadIdx.x; i < 14400; i += blockDim.x) {
        unsigned int v = cm[i];
        if (v > 1u) lw = 1;
        if ((v & 0xFFu) > 1u || ((v >> 8) & 0xFFu) > 1u ||
            ((v >> 16) & 0xFFu) > 1u || ((v >> 24) & 0xFFu) > 1u) lb = 1;
    }
    if (lw) atomicOr(&word_gt1, 1);
    if (lb) atomicOr(&byte_gt1, 1);
    __syncthreads();
    if (threadIdx.x == 0) {
        int f = 0;                       // all words 0/1 -> int32
        if (word_gt1) f = byte_gt1 ? 2 : 1; // bytes>1 -> f32, else packed bool
        *flag_out = f;
    }
}

// ---------------- K1: gather + masked mean pool ----------------
// one block per (b,h); 256 threads, 3 columns each
__global__ __launch_bounds__(256) void k1_pool(
        const int* __restrict__ enc, const void* amask,
        const float* __restrict__ wemb, float* __restrict__ pooled,
        const int* __restrict__ flagp) {
    int bh = blockIdx.x;                 // [0,3200)
    int t  = threadIdx.x;
    int flag = *flagp;
    const int* e = enc + bh * SEQ;
    float a0 = 0.f, a1 = 0.f, a2 = 0.f, cnt = 0.f;
    #pragma unroll 4
    for (int s = 0; s < SEQ; ++s) {
        float m = read_mask(amask, bh * SEQ + s, flag) ? 1.0f : 0.0f;
        const float* row = wemb + (size_t)e[s] * EMBED;
        a0 += m * row[t];
        a1 += m * row[t + 256];
        a2 += m * row[t + 512];
        cnt += m;
    }
    float d = 1.0f / fmaxf(cnt, 1.0f);
    float* o = pooled + (size_t)bh * EMBED;
    o[t] = a0 * d; o[t + 256] = a1 * d; o[t + 512] = a2 * d;
}

// ---------------- K2: news_repr = tanh(pooled @ W + b) ----------------
// f32 SGEMM: 64x64 block tile, 16x16 threads, 4x4 micro-tile, K-chunk 16
#define TK 16
__global__ __launch_bounds__(256) void k2_gemm(
        const float* __restrict__ A,     // pooled [3200][768]
        const float* __restrict__ W,     // [768][768]
        const float* __restrict__ bias,  // [768]
        float* __restrict__ C) {         // news_repr [3200][768]
    __shared__ float AsT[TK][72];        // A transposed: [kk][r], stride 72 keeps 16B align
    __shared__ float Bs [TK][72];        // [kk][c]
    int tid = threadIdx.x;
    int tx = tid & 15, ty = tid >> 4;
    int row0 = blockIdx.x * 64;          // 50 row-blocks (3200/64)
    int col0 = blockIdx.y * 64;          // 12 col-blocks
    float acc[4][4] = {};
    for (int k0 = 0; k0 < EMBED; k0 += TK) {
        #pragma unroll
        for (int it = 0; it < 4; ++it) {
            int lin = tid + it * 256;    // [0,1024)
            int r  = lin >> 4, kk = lin & 15;
            AsT[kk][r] = A[(size_t)(row0 + r) * EMBED + k0 + kk];
            int kb = lin >> 6, c = lin & 63;
            Bs[kb][c] = W[(size_t)(k0 + kb) * EMBED + col0 + c];
        }
        __syncthreads();
        #pragma unroll
        for (int kk = 0; kk < TK; ++kk) {
            float4 av = *(const float4*)&AsT[kk][ty * 4];
            float4 bv = *(const float4*)&Bs[kk][tx * 4];
            float aa[4] = {av.x, av.y, av.z, av.w};
            float bb[4] = {bv.x, bv.y, bv.z, bv.w};
            #pragma unroll
            for (int i = 0; i < 4; ++i)
                #pragma unroll
                for (int j = 0; j < 4; ++j)
                    acc[i][j] += aa[i] * bb[j];
        }
        __syncthreads();
    }
    #pragma unroll
    for (int i = 0; i < 4; ++i) {
        int r = row0 + ty * 4 + i;
        #pragma unroll
        for (int j = 0; j < 4; ++j) {
            int cc = col0 + tx * 4 + j;
            C[(size_t)r * EMBED + cc] = tanhf(acc[i][j] + bias[cc]);
        }
    }
}

// ---------------- K3: news_w = news_repr @ w_news_attn ----------------
// one wave per row
__global__ __launch_bounds__(256) void k3_newsw(
        const float* __restrict__ nr, const float* __restrict__ w,
        float* __restrict__ news_w) {
    int wave = threadIdx.x >> 6;
    int lane = threadIdx.x & 63;
    int row = blockIdx.x * 4 + wave;     // 800 blocks * 4 waves = 3200
    const float* r = nr + (size_t)row * EMBED;
    float s = 0.f;
    #pragma unroll
    for (int e = lane; e < EMBED; e += 64) s += r[e] * w[e];
    #pragma unroll
    for (int off = 32; off; off >>= 1) s += __shfl_down(s, off);
    if (lane == 0) news_w[row] = s;
}

// ---------------- K4: per-(b,c) masked softmax attention + category_repr ----------------
__global__ __launch_bounds__(256) void k4_cat(
        const void* cmask, const float* __restrict__ news_w,
        const float* __restrict__ nr, const float* __restrict__ cat_emb,
        const float* __restrict__ w_cat, const float* __restrict__ click_emb,
        const float* __restrict__ click_w, const float* __restrict__ click_b,
        float* __restrict__ out_cat, float* __restrict__ flogit,
        const int* __restrict__ flagp) {
    int b = blockIdx.x / NUM_CAT, c = blockIdx.x % NUM_CAT;
    int t = threadIdx.x;
    int flag = *flagp;
    __shared__ float p[HIS];
    __shared__ float red[4];
    if (t < HIS) {
        bool m = read_mask(cmask, (b * NUM_CAT + c) * HIS + t, flag);
        p[t] = m ? news_w[b * HIS + t] : -INFINITY;
    }
    __syncthreads();
    // redundant per-thread reduction over 50 (broadcast LDS reads)
    float maxv = -INFINITY; int cnt = 0;
    #pragma unroll
    for (int h = 0; h < HIS; ++h) {
        float v = p[h];
        if (v > -INFINITY) cnt++;
        maxv = fmaxf(maxv, v);
    }
    float sum = 0.f;
    #pragma unroll
    for (int h = 0; h < HIS; ++h) {
        float v = p[h];
        sum += (v == -INFINITY) ? 0.f : expf(v - maxv);
    }
    __syncthreads();
    if (t < HIS) {
        float v = p[t];
        p[t] = (cnt == 0 || v == -INFINITY) ? 0.f : expf(v - maxv) / sum;
    }
    __syncthreads();
    // category_interest + category_embedding; fused cat_w dot
    float catw_local = 0.f;
    #pragma unroll
    for (int i = 0; i < 3; ++i) {
        int e = t + i * 256;
        float ci = 0.f;
        for (int h = 0; h < HIS; ++h)
            ci += p[h] * nr[(size_t)(b * HIS + h) * EMBED + e];
        float v = ci + cat_emb[c * EMBED + e];
        out_cat[(size_t)(b * NUM_CAT + c) * EMBED + e] = v;
        catw_local += v * w_cat[e];
    }
    float s = catw_local;
    #pragma unroll
    for (int off = 32; off; off >>= 1) s += __shfl_down(s, off);
    int lane = t & 63, wv = t >> 6;
    if (lane == 0) red[wv] = s;
    __syncthreads();
    if (t == 0) {
        float catw = red[0] + red[1] + red[2] + red[3];
        float click = 0.f;
        const float* ce = click_emb + cnt * CLICK_DIM;
        for (int d = 0; d < CLICK_DIM; ++d) click += ce[d] * click_w[d];
        click += click_b[0];
        flogit[b * NUM_CAT + c] = (cnt == 0) ? -INFINITY : (catw + click);
    }
}

// ---------------- K5: final softmax over C + user_repr ----------------
__global__ __launch_bounds__(256) void k5_user(
        const float* __restrict__ flogit, const float* __restrict__ cat_repr,
        float* __restrict__ user) {
    int b = blockIdx.x, t = threadIdx.x;
    __shared__ float p[NUM_CAT];
    if (t < NUM_CAT) p[t] = flogit[b * NUM_CAT + t];
    __syncthreads();
    float maxv = -INFINITY;
    #pragma unroll
    for (int c = 0; c < NUM_CAT; ++c) maxv = fmaxf(maxv, p[c]);
    float sum = 0.f;
    #pragma unroll
    for (int c = 0; c < NUM_CAT; ++c)
        sum += (p[c] == -INFINITY) ? 0.f : expf(p[c] - maxv);
    float w[NUM_CAT];
    #pragma unroll
    for (int c = 0; c < NUM_CAT; ++c)
        w[c] = (p[c] == -INFINITY) ? 0.f : expf(p[c] - maxv) / sum;
    #pragma unroll
    for (int i = 0; i < 3; ++i) {
        int e = t + i * 256;
        float acc = 0.f;
        #pragma unroll
        for (int c = 0; c < NUM_CAT; ++c)
            acc += w[c] * cat_repr[(size_t)(b * NUM_CAT + c) * EMBED + e];
        user[(size_t)b * EMBED + e] = acc;
    }
}

extern "C" void kernel_launch(void* const* d_in, const int* in_sizes, int n_in,
                              void* d_out, int out_size, void* d_ws, size_t ws_size,
                              hipStream_t stream) {
    const int*   enc    = (const int*)d_in[0];
    const void*  amask  = d_in[1];
    const void*  cmask  = d_in[2];
    const float* wemb   = (const float*)d_in[3];
    const float* projw  = (const float*)d_in[4];
    const float* projb  = (const float*)d_in[5];
    const float* catemb = (const float*)d_in[6];
    const float* wna    = (const float*)d_in[7];
    const float* wca    = (const float*)d_in[8];
    const float* clemb  = (const float*)d_in[9];
    const float* clw    = (const float*)d_in[10];
    const float* clb    = (const float*)d_in[11];

    float* ws      = (float*)d_ws;
    float* pooled  = ws + WS_POOLED;
    float* nr      = ws + WS_NR;
    float* news_w  = ws + WS_NEWSW;
    float* flogit  = ws + WS_LOGIT;
    int*   flag    = (int*)(ws + WS_FLAG);

    float* out_cat = (float*)d_out;                          // [64,18,768]
    float* user    = (float*)d_out + BATCH * NUM_CAT * EMBED; // [64,768]

    k0_detect<<<1, 256, 0, stream>>>((const unsigned int*)cmask, flag);
    k1_pool<<<BATCH * HIS, 256, 0, stream>>>(enc, amask, wemb, pooled, flag);
    dim3 g2(50, 12);
    k2_gemm<<<g2, 256, 0, stream>>>(pooled, projw, projb, nr);
    k3_newsw<<<800, 256, 0, stream>>>(nr, wna, news_w);
    k4_cat<<<BATCH * NUM_CAT, 256, 0, stream>>>(cmask, news_w, nr, catemb, wca,
                                                clemb, clw, clb, out_cat, flogit, flag);
    k5_user<<<BATCH, 256, 0, stream>>>(flogit, out_cat, user);
}

// Round 2
// 141.985 us; speedup vs baseline: 1.4127x; 1.4127x over previous
//
#include <hip/hip_runtime.h>
#include <hip/hip_bf16.h>
#include <math.h>

#define VOCAB 30522
#define EMBED 768
#define NUM_CAT 18
#define HIS 50
#define SEQ 32
#define BATCH 64
#define CLICK_DIM 100

typedef short v8s __attribute__((ext_vector_type(8)));
typedef float v4f __attribute__((ext_vector_type(4)));

// ---------------- ws layout (byte offsets, all 16B aligned) ----------------
// pooled bf16 [3200][768] : 0          .. 4,915,200
// Wt     bf16 [768][768]  : 4,915,200  .. 6,094,848   (Wt[n][k] = W[k][n])
// nr     f32  [3200][768] : 6,094,848  .. 15,925,248
// news_w f32  [3200]      : 15,925,248 .. 15,938,048
// flogit f32  [64*18]     : 15,938,048 .. 15,942,656
// flag   int              : 15,942,656
#define OFF_POOLED 0
#define OFF_WT     4915200
#define OFF_NR     6094848
#define OFF_NEWSW  15925248
#define OFF_LOGIT  15938048
#define OFF_FLAG   15942656

// flag: 0 = int32 mask, 1 = uint8 (np.bool_) mask, 2 = float32 mask
__device__ __forceinline__ bool read_mask(const void* p, int i, int flag) {
    if (flag == 0) return ((const int*)p)[i] != 0;
    if (flag == 1) return ((const unsigned char*)p)[i] != 0;
    return ((const float*)p)[i] != 0.0f;
}

// ---------------- K0: detect bool layout from category_mask ----------------
__global__ void k0_detect(const unsigned int* __restrict__ cm, int* flag_out) {
    __shared__ int word_gt1, byte_gt1;
    if (threadIdx.x == 0) { word_gt1 = 0; byte_gt1 = 0; }
    __syncthreads();
    int lw = 0, lb = 0;
    for (int i = threadIdx.x; i < 14400; i += blockDim.x) {
        unsigned int v = cm[i];
        if (v > 1u) lw = 1;
        if ((v & 0xFFu) > 1u || ((v >> 8) & 0xFFu) > 1u ||
            ((v >> 16) & 0xFFu) > 1u || ((v >> 24) & 0xFFu) > 1u) lb = 1;
    }
    if (lw) atomicOr(&word_gt1, 1);
    if (lb) atomicOr(&byte_gt1, 1);
    __syncthreads();
    if (threadIdx.x == 0) {
        int f = 0;
        if (word_gt1) f = byte_gt1 ? 2 : 1;
        *flag_out = f;
    }
}

// ---------------- K1: gather + masked mean pool -> pooled (bf16) ----------------
// one wave per (b,h); lane handles 3 float4 column slots; 800 blocks x 4 waves
__global__ __launch_bounds__(256) void k1_pool(
        const int* __restrict__ enc, const void* amask,
        const float* __restrict__ wemb, __hip_bfloat16* __restrict__ pooled,
        const int* __restrict__ flagp) {
    int wave = threadIdx.x >> 6, lane = threadIdx.x & 63;
    int bh = blockIdx.x * 4 + wave;      // [0,3200)
    int flag = *flagp;
    const int* e = enc + bh * SEQ;
    float a[12] = {};
    float cnt = 0.f;
    #pragma unroll 4
    for (int s = 0; s < SEQ; ++s) {
        int tok = e[s];                  // lane-uniform -> scalar load
        float m = read_mask(amask, bh * SEQ + s, flag) ? 1.0f : 0.0f;
        const float4* row = (const float4*)(wemb + (size_t)tok * EMBED);
        float4 v0 = row[lane], v1 = row[lane + 64], v2 = row[lane + 128];
        a[0] += m * v0.x; a[1]  += m * v0.y; a[2]  += m * v0.z; a[3]  += m * v0.w;
        a[4] += m * v1.x; a[5]  += m * v1.y; a[6]  += m * v1.z; a[7]  += m * v1.w;
        a[8] += m * v2.x; a[9]  += m * v2.y; a[10] += m * v2.z; a[11] += m * v2.w;
        cnt += m;
    }
    float d = 1.0f / fmaxf(cnt, 1.0f);
    __hip_bfloat16* o = pooled + (size_t)bh * EMBED;
    #pragma unroll
    for (int i = 0; i < 3; ++i) {
        union { ushort4 u; unsigned short s[4]; } pk;
        #pragma unroll
        for (int j = 0; j < 4; ++j) {
            __hip_bfloat16 h = __float2bfloat16(a[i * 4 + j] * d);
            pk.s[j] = *(unsigned short*)&h;
        }
        *(ushort4*)(o + (size_t)i * 256 + lane * 4) = pk.u;
    }
}

// ---------------- K2a: Wt[n][k] = bf16(W[k][n]) ----------------
__global__ __launch_bounds__(256) void k2a_wt(
        const float* __restrict__ W, __hip_bfloat16* __restrict__ Wt) {
    __shared__ float t[32][33];
    int tx = threadIdx.x & 31, ty = threadIdx.x >> 5;   // 32 x 8
    int k0 = blockIdx.x * 32, n0 = blockIdx.y * 32;
    #pragma unroll
    for (int i = 0; i < 4; ++i)
        t[ty + i * 8][tx] = W[(size_t)(k0 + ty + i * 8) * EMBED + n0 + tx];
    __syncthreads();
    #pragma unroll
    for (int i = 0; i < 4; ++i)
        Wt[(size_t)(n0 + ty + i * 8) * EMBED + k0 + tx] =
            __float2bfloat16(t[tx][ty + i * 8]);
}

// ---------------- K2: news_repr = tanh(pooled @ W + b), bf16 MFMA ----------------
// 128x128 tile, BK=64, 4 waves (2x2, each 64x64 = 4x4 frags of 16x16x32)
// LDS rows padded to 72 bf16 (144B): bank = (4r+4c)%32 -> (r+c)%8 uniform, conflict-free
#define GBM 128
#define GBK 64
#define LDP 72
__global__ __launch_bounds__(256) void k2_mfma(
        const __hip_bfloat16* __restrict__ A,   // pooled [3200][768]
        const __hip_bfloat16* __restrict__ Bt,  // Wt [768(n)][768(k)]
        const float* __restrict__ bias,
        float* __restrict__ C) {                // news_repr [3200][768]
    __shared__ short As[GBM * LDP];
    __shared__ short Bs[GBM * LDP];
    int tid = threadIdx.x;
    int wave = tid >> 6, lane = tid & 63;
    int l15 = lane & 15, l4 = lane >> 4;
    int wr = wave >> 1, wc = wave & 1;
    int row0 = blockIdx.x * GBM;         // 25 blocks
    int col0 = blockIdx.y * GBM;         // 6 blocks
    v4f acc[4][4] = {};

    // per-thread staging coords: chunk = tid + it*256 -> r=chunk>>3, c=chunk&7
    int r_st[4], c_st[4];
    #pragma unroll
    for (int it = 0; it < 4; ++it) {
        int chunk = tid + it * 256;
        r_st[it] = chunk >> 3; c_st[it] = chunk & 7;
    }

    v8s pa[4], pb[4];
    #pragma unroll
    for (int it = 0; it < 4; ++it) {
        pa[it] = *(const v8s*)(A  + (size_t)(row0 + r_st[it]) * EMBED + c_st[it] * 8);
        pb[it] = *(const v8s*)(Bt + (size_t)(col0 + r_st[it]) * EMBED + c_st[it] * 8);
    }

    for (int s = 0; s < EMBED / GBK; ++s) {
        #pragma unroll
        for (int it = 0; it < 4; ++it) {
            *(v8s*)&As[r_st[it] * LDP + c_st[it] * 8] = pa[it];
            *(v8s*)&Bs[r_st[it] * LDP + c_st[it] * 8] = pb[it];
        }
        __syncthreads();
        if (s < EMBED / GBK - 1) {
            int k0 = (s + 1) * GBK;
            #pragma unroll
            for (int it = 0; it < 4; ++it) {
                pa[it] = *(const v8s*)(A  + (size_t)(row0 + r_st[it]) * EMBED + k0 + c_st[it] * 8);
                pb[it] = *(const v8s*)(Bt + (size_t)(col0 + r_st[it]) * EMBED + k0 + c_st[it] * 8);
            }
        }
        #pragma unroll
        for (int kk = 0; kk < 2; ++kk) {
            v8s af[4], bf_[4];
            #pragma unroll
            for (int mi = 0; mi < 4; ++mi)
                af[mi] = *(const v8s*)&As[(wr * 64 + mi * 16 + l15) * LDP + kk * 32 + l4 * 8];
            #pragma unroll
            for (int ni = 0; ni < 4; ++ni)
                bf_[ni] = *(const v8s*)&Bs[(wc * 64 + ni * 16 + l15) * LDP + kk * 32 + l4 * 8];
            #pragma unroll
            for (int mi = 0; mi < 4; ++mi)
                #pragma unroll
                for (int ni = 0; ni < 4; ++ni)
                    acc[mi][ni] = __builtin_amdgcn_mfma_f32_16x16x32_bf16(
                        af[mi], bf_[ni], acc[mi][ni], 0, 0, 0);
        }
        __syncthreads();
    }
    // epilogue: C/D map col=lane&15, row=(lane>>4)*4+reg
    #pragma unroll
    for (int mi = 0; mi < 4; ++mi) {
        #pragma unroll
        for (int ni = 0; ni < 4; ++ni) {
            int col = col0 + wc * 64 + ni * 16 + l15;
            float b = bias[col];
            #pragma unroll
            for (int r = 0; r < 4; ++r) {
                int row = row0 + wr * 64 + mi * 16 + l4 * 4 + r;
                C[(size_t)row * EMBED + col] = tanhf(acc[mi][ni][r] + b);
            }
        }
    }
}

// ---------------- K3: news_w = news_repr @ w_news_attn ----------------
__global__ __launch_bounds__(256) void k3_newsw(
        const float* __restrict__ nr, const float* __restrict__ w,
        float* __restrict__ news_w) {
    int wave = threadIdx.x >> 6;
    int lane = threadIdx.x & 63;
    int row = blockIdx.x * 4 + wave;
    const float* r = nr + (size_t)row * EMBED;
    float s = 0.f;
    #pragma unroll
    for (int e = lane; e < EMBED; e += 64) s += r[e] * w[e];
    #pragma unroll
    for (int off = 32; off; off >>= 1) s += __shfl_down(s, off);
    if (lane == 0) news_w[row] = s;
}

// ---------------- K4: per-(b,c) masked softmax attention + category_repr ----------------
__global__ __launch_bounds__(256) void k4_cat(
        const void* cmask, const float* __restrict__ news_w,
        const float* __restrict__ nr, const float* __restrict__ cat_emb,
        const float* __restrict__ w_cat, const float* __restrict__ click_emb,
        const float* __restrict__ click_w, const float* __restrict__ click_b,
        float* __restrict__ out_cat, float* __restrict__ flogit,
        const int* __restrict__ flagp) {
    int b = blockIdx.x / NUM_CAT, c = blockIdx.x % NUM_CAT;
    int t = threadIdx.x;
    int flag = *flagp;
    __shared__ float p[HIS];
    __shared__ float red[4];
    if (t < HIS) {
        bool m = read_mask(cmask, (b * NUM_CAT + c) * HIS + t, flag);
        p[t] = m ? news_w[b * HIS + t] : -INFINITY;
    }
    __syncthreads();
    float maxv = -INFINITY; int cnt = 0;
    #pragma unroll
    for (int h = 0; h < HIS; ++h) {
        float v = p[h];
        if (v > -INFINITY) cnt++;
        maxv = fmaxf(maxv, v);
    }
    float sum = 0.f;
    #pragma unroll
    for (int h = 0; h < HIS; ++h) {
        float v = p[h];
        sum += (v == -INFINITY) ? 0.f : expf(v - maxv);
    }
    __syncthreads();
    if (t < HIS) {
        float v = p[t];
        p[t] = (cnt == 0 || v == -INFINITY) ? 0.f : expf(v - maxv) / sum;
    }
    __syncthreads();
    float catw_local = 0.f;
    #pragma unroll
    for (int i = 0; i < 3; ++i) {
        int e = t + i * 256;
        float ci = 0.f;
        for (int h = 0; h < HIS; ++h)
            ci += p[h] * nr[(size_t)(b * HIS + h) * EMBED + e];
        float v = ci + cat_emb[c * EMBED + e];
        out_cat[(size_t)(b * NUM_CAT + c) * EMBED + e] = v;
        catw_local += v * w_cat[e];
    }
    float s = catw_local;
    #pragma unroll
    for (int off = 32; off; off >>= 1) s += __shfl_down(s, off);
    int lane = t & 63, wv = t >> 6;
    if (lane == 0) red[wv] = s;
    __syncthreads();
    if (t == 0) {
        float catw = red[0] + red[1] + red[2] + red[3];
        float click = 0.f;
        const float* ce = click_emb + cnt * CLICK_DIM;
        for (int d = 0; d < CLICK_DIM; ++d) click += ce[d] * click_w[d];
        click += click_b[0];
        flogit[b * NUM_CAT + c] = (cnt == 0) ? -INFINITY : (catw + click);
    }
}

// ---------------- K5: final softmax over C + user_repr ----------------
__global__ __launch_bounds__(256) void k5_user(
        const float* __restrict__ flogit, const float* __restrict__ cat_repr,
        float* __restrict__ user) {
    int b = blockIdx.x, t = threadIdx.x;
    __shared__ float p[NUM_CAT];
    if (t < NUM_CAT) p[t] = flogit[b * NUM_CAT + t];
    __syncthreads();
    float maxv = -INFINITY;
    #pragma unroll
    for (int c = 0; c < NUM_CAT; ++c) maxv = fmaxf(maxv, p[c]);
    float sum = 0.f;
    #pragma unroll
    for (int c = 0; c < NUM_CAT; ++c)
        sum += (p[c] == -INFINITY) ? 0.f : expf(p[c] - maxv);
    float w[NUM_CAT];
    #pragma unroll
    for (int c = 0; c < NUM_CAT; ++c)
        w[c] = (p[c] == -INFINITY) ? 0.f : expf(p[c] - maxv) / sum;
    #pragma unroll
    for (int i = 0; i < 3; ++i) {
        int e = t + i * 256;
        float acc = 0.f;
        #pragma unroll
        for (int c = 0; c < NUM_CAT; ++c)
            acc += w[c] * cat_repr[(size_t)(b * NUM_CAT + c) * EMBED + e];
        user[(size_t)b * EMBED + e] = acc;
    }
}

extern "C" void kernel_launch(void* const* d_in, const int* in_sizes, int n_in,
                              void* d_out, int out_size, void* d_ws, size_t ws_size,
                              hipStream_t stream) {
    const int*   enc    = (const int*)d_in[0];
    const void*  amask  = d_in[1];
    const void*  cmask  = d_in[2];
    const float* wemb   = (const float*)d_in[3];
    const float* projw  = (const float*)d_in[4];
    const float* projb  = (const float*)d_in[5];
    const float* catemb = (const float*)d_in[6];
    const float* wna    = (const float*)d_in[7];
    const float* wca    = (const float*)d_in[8];
    const float* clemb  = (const float*)d_in[9];
    const float* clw    = (const float*)d_in[10];
    const float* clb    = (const float*)d_in[11];

    unsigned char* wsb = (unsigned char*)d_ws;
    __hip_bfloat16* pooled = (__hip_bfloat16*)(wsb + OFF_POOLED);
    __hip_bfloat16* Wt     = (__hip_bfloat16*)(wsb + OFF_WT);
    float* nr      = (float*)(wsb + OFF_NR);
    float* news_w  = (float*)(wsb + OFF_NEWSW);
    float* flogit  = (float*)(wsb + OFF_LOGIT);
    int*   flag    = (int*)(wsb + OFF_FLAG);

    float* out_cat = (float*)d_out;
    float* user    = (float*)d_out + BATCH * NUM_CAT * EMBED;

    k0_detect<<<1, 256, 0, stream>>>((const unsigned int*)cmask, flag);
    dim3 gt(24, 24);
    k2a_wt<<<gt, 256, 0, stream>>>(projw, Wt);
    k1_pool<<<800, 256, 0, stream>>>(enc, amask, wemb, pooled, flag);
    dim3 g2(25, 6);
    k2_mfma<<<g2, 256, 0, stream>>>(pooled, Wt, projb, nr);
    k3_newsw<<<800, 256, 0, stream>>>(nr, wna, news_w);
    k4_cat<<<BATCH * NUM_CAT, 256, 0, stream>>>(cmask, news_w, nr, catemb, wca,
                                                clemb, clw, clb, out_cat, flogit, flag);
    k5_user<<<BATCH, 256, 0, stream>>>(flogit, out_cat, user);
}

// Round 3
// 129.242 us; speedup vs baseline: 1.5520x; 1.0986x over previous
//
#include <hip/hip_runtime.h>
#include <hip/hip_bf16.h>
#include <math.h>

#define VOCAB 30522
#define EMBED 768
#define NUM_CAT 18
#define HIS 50
#define SEQ 32
#define BATCH 64
#define CLICK_DIM 100

typedef short v8s __attribute__((ext_vector_type(8)));
typedef float v4f __attribute__((ext_vector_type(4)));

// ---------------- ws layout (byte offsets, 16B aligned) ----------------
#define OFF_POOLED 0            // bf16 [3200][768]           4,915,200 B
#define OFF_WT     4915200      // bf16 [768][768]            1,179,648 B
#define OFF_NR     6094848      // f32  [3200][768]           9,830,400 B
#define OFF_NEWSW  15925248     // f32  [3200]                   12,800 B
#define OFF_ATTN   15938048     // f32  [64*18][50]             230,400 B
#define OFF_CNT    16168448     // int  [64*18]                   4,608 B
#define OFF_LOGIT  16173056     // f32  [64*18]                   4,608 B
#define OFF_FLAG   16177664     // int

// flag: 0 = int32 mask, 1 = uint8 (np.bool_) mask, 2 = float32 mask
__device__ __forceinline__ bool read_mask(const void* p, int i, int flag) {
    if (flag == 0) return ((const int*)p)[i] != 0;
    if (flag == 1) return ((const unsigned char*)p)[i] != 0;
    return ((const float*)p)[i] != 0.0f;
}

// ---------------- K0: detect bool layout from category_mask ----------------
__global__ void k0_detect(const unsigned int* __restrict__ cm, int* flag_out) {
    __shared__ int word_gt1, byte_gt1;
    if (threadIdx.x == 0) { word_gt1 = 0; byte_gt1 = 0; }
    __syncthreads();
    int lw = 0, lb = 0;
    for (int i = threadIdx.x; i < 14400; i += blockDim.x) {
        unsigned int v = cm[i];
        if (v > 1u) lw = 1;
        if ((v & 0xFFu) > 1u || ((v >> 8) & 0xFFu) > 1u ||
            ((v >> 16) & 0xFFu) > 1u || ((v >> 24) & 0xFFu) > 1u) lb = 1;
    }
    if (lw) atomicOr(&word_gt1, 1);
    if (lb) atomicOr(&byte_gt1, 1);
    __syncthreads();
    if (threadIdx.x == 0) {
        int f = 0;
        if (word_gt1) f = byte_gt1 ? 2 : 1;
        *flag_out = f;
    }
}

// ---------------- K1: gather + masked mean pool -> pooled (bf16) ----------------
// one wave per (b,h,256-col slot): grid 3200 x 192 threads = 9600 waves
__global__ __launch_bounds__(192) void k1_pool(
        const int* __restrict__ enc, const void* amask,
        const float* __restrict__ wemb, __hip_bfloat16* __restrict__ pooled,
        const int* __restrict__ flagp) {
    int wave = threadIdx.x >> 6, lane = threadIdx.x & 63;
    int bh = blockIdx.x;                 // [0,3200)
    int flag = *flagp;
    const int* e = enc + bh * SEQ;
    int fslot = wave * 64 + lane;        // float4 index within row [0,192)
    float ax = 0.f, ay = 0.f, az = 0.f, aw = 0.f, cnt = 0.f;
    #pragma unroll 8
    for (int s = 0; s < SEQ; ++s) {
        int tok = e[s];                  // lane-uniform -> scalar load
        float m = read_mask(amask, bh * SEQ + s, flag) ? 1.0f : 0.0f;
        float4 v = ((const float4*)(wemb + (size_t)tok * EMBED))[fslot];
        ax += m * v.x; ay += m * v.y; az += m * v.z; aw += m * v.w;
        cnt += m;
    }
    float d = 1.0f / fmaxf(cnt, 1.0f);
    union { ushort4 u; unsigned short s[4]; } pk;
    __hip_bfloat16 h0 = __float2bfloat16(ax * d); pk.s[0] = *(unsigned short*)&h0;
    __hip_bfloat16 h1 = __float2bfloat16(ay * d); pk.s[1] = *(unsigned short*)&h1;
    __hip_bfloat16 h2 = __float2bfloat16(az * d); pk.s[2] = *(unsigned short*)&h2;
    __hip_bfloat16 h3 = __float2bfloat16(aw * d); pk.s[3] = *(unsigned short*)&h3;
    *(ushort4*)(pooled + (size_t)bh * EMBED + fslot * 4) = pk.u;
}

// ---------------- K2a: Wt[n][k] = bf16(W[k][n]) ----------------
__global__ __launch_bounds__(256) void k2a_wt(
        const float* __restrict__ W, __hip_bfloat16* __restrict__ Wt) {
    __shared__ float t[32][33];
    int tx = threadIdx.x & 31, ty = threadIdx.x >> 5;   // 32 x 8
    int k0 = blockIdx.x * 32, n0 = blockIdx.y * 32;
    #pragma unroll
    for (int i = 0; i < 4; ++i)
        t[ty + i * 8][tx] = W[(size_t)(k0 + ty + i * 8) * EMBED + n0 + tx];
    __syncthreads();
    #pragma unroll
    for (int i = 0; i < 4; ++i)
        Wt[(size_t)(n0 + ty + i * 8) * EMBED + k0 + tx] =
            __float2bfloat16(t[tx][ty + i * 8]);
}

// ---------------- K2: news_repr = tanh(pooled @ W + b), bf16 MFMA ----------------
#define GBM 128
#define GBK 64
#define LDP 72
__global__ __launch_bounds__(256) void k2_mfma(
        const __hip_bfloat16* __restrict__ A,   // pooled [3200][768]
        const __hip_bfloat16* __restrict__ Bt,  // Wt [768(n)][768(k)]
        const float* __restrict__ bias,
        float* __restrict__ C) {                // news_repr [3200][768]
    __shared__ short As[GBM * LDP];
    __shared__ short Bs[GBM * LDP];
    int tid = threadIdx.x;
    int wave = tid >> 6, lane = tid & 63;
    int l15 = lane & 15, l4 = lane >> 4;
    int wr = wave >> 1, wc = wave & 1;
    int row0 = blockIdx.x * GBM;
    int col0 = blockIdx.y * GBM;
    v4f acc[4][4] = {};

    int r_st[4], c_st[4];
    #pragma unroll
    for (int it = 0; it < 4; ++it) {
        int chunk = tid + it * 256;
        r_st[it] = chunk >> 3; c_st[it] = chunk & 7;
    }

    v8s pa[4], pb[4];
    #pragma unroll
    for (int it = 0; it < 4; ++it) {
        pa[it] = *(const v8s*)(A  + (size_t)(row0 + r_st[it]) * EMBED + c_st[it] * 8);
        pb[it] = *(const v8s*)(Bt + (size_t)(col0 + r_st[it]) * EMBED + c_st[it] * 8);
    }

    for (int s = 0; s < EMBED / GBK; ++s) {
        #pragma unroll
        for (int it = 0; it < 4; ++it) {
            *(v8s*)&As[r_st[it] * LDP + c_st[it] * 8] = pa[it];
            *(v8s*)&Bs[r_st[it] * LDP + c_st[it] * 8] = pb[it];
        }
        __syncthreads();
        if (s < EMBED / GBK - 1) {
            int k0 = (s + 1) * GBK;
            #pragma unroll
            for (int it = 0; it < 4; ++it) {
                pa[it] = *(const v8s*)(A  + (size_t)(row0 + r_st[it]) * EMBED + k0 + c_st[it] * 8);
                pb[it] = *(const v8s*)(Bt + (size_t)(col0 + r_st[it]) * EMBED + k0 + c_st[it] * 8);
            }
        }
        #pragma unroll
        for (int kk = 0; kk < 2; ++kk) {
            v8s af[4], bf_[4];
            #pragma unroll
            for (int mi = 0; mi < 4; ++mi)
                af[mi] = *(const v8s*)&As[(wr * 64 + mi * 16 + l15) * LDP + kk * 32 + l4 * 8];
            #pragma unroll
            for (int ni = 0; ni < 4; ++ni)
                bf_[ni] = *(const v8s*)&Bs[(wc * 64 + ni * 16 + l15) * LDP + kk * 32 + l4 * 8];
            #pragma unroll
            for (int mi = 0; mi < 4; ++mi)
                #pragma unroll
                for (int ni = 0; ni < 4; ++ni)
                    acc[mi][ni] = __builtin_amdgcn_mfma_f32_16x16x32_bf16(
                        af[mi], bf_[ni], acc[mi][ni], 0, 0, 0);
        }
        __syncthreads();
    }
    #pragma unroll
    for (int mi = 0; mi < 4; ++mi) {
        #pragma unroll
        for (int ni = 0; ni < 4; ++ni) {
            int col = col0 + wc * 64 + ni * 16 + l15;
            float b = bias[col];
            #pragma unroll
            for (int r = 0; r < 4; ++r) {
                int row = row0 + wr * 64 + mi * 16 + l4 * 4 + r;
                C[(size_t)row * EMBED + col] = tanhf(acc[mi][ni][r] + b);
            }
        }
    }
}

// ---------------- K3: news_w = news_repr @ w_news_attn ----------------
__global__ __launch_bounds__(256) void k3_newsw(
        const float* __restrict__ nr, const float* __restrict__ w,
        float* __restrict__ news_w) {
    int wave = threadIdx.x >> 6;
    int lane = threadIdx.x & 63;
    int row = blockIdx.x * 4 + wave;
    const float* r = nr + (size_t)row * EMBED;
    float s = 0.f;
    #pragma unroll
    for (int e = lane; e < EMBED; e += 64) s += r[e] * w[e];
    #pragma unroll
    for (int off = 32; off; off >>= 1) s += __shfl_down(s, off);
    if (lane == 0) news_w[row] = s;
}

// ---------------- K4a: per-(b,c) masked softmax -> attn weights + counts ----------------
// one wave per (b,c): 288 blocks x 4 waves = 1152
__global__ __launch_bounds__(256) void k4a_attn(
        const void* cmask, const float* __restrict__ news_w,
        float* __restrict__ attn, int* __restrict__ cntws,
        const int* __restrict__ flagp) {
    int wave = threadIdx.x >> 6, lane = threadIdx.x & 63;
    int w = blockIdx.x * 4 + wave;       // [0,1152)
    int b = w / NUM_CAT, c = w % NUM_CAT;
    int flag = *flagp;
    bool m = false;
    float v = -INFINITY;
    if (lane < HIS) {
        m = read_mask(cmask, (b * NUM_CAT + c) * HIS + lane, flag);
        if (m) v = news_w[b * HIS + lane];
    }
    unsigned long long bal = __ballot(m && lane < HIS);
    int cnt = __popcll(bal);
    float maxv = v;
    #pragma unroll
    for (int off = 32; off; off >>= 1) maxv = fmaxf(maxv, __shfl_xor(maxv, off));
    float e = (v == -INFINITY) ? 0.f : expf(v - maxv);
    float sum = e;
    #pragma unroll
    for (int off = 32; off; off >>= 1) sum += __shfl_xor(sum, off);
    if (lane < HIS)
        attn[w * HIS + lane] = (cnt == 0 || v == -INFINITY) ? 0.f : e / sum;
    if (lane == 0) cntws[w] = cnt;
}

// ---------------- K4b: category_repr = attn @ nr + cat_emb ----------------
// one block per b, 192 threads; thread owns float4 col slot; nr[b] read ONCE
__global__ __launch_bounds__(192) void k4b_catrep(
        const float* __restrict__ attn, const float* __restrict__ nr,
        const float* __restrict__ cat_emb, float* __restrict__ out_cat) {
    int b = blockIdx.x, tid = threadIdx.x;
    __shared__ float plds[NUM_CAT * HIS];
    for (int i = tid; i < NUM_CAT * HIS; i += 192)
        plds[i] = attn[b * NUM_CAT * HIS + i];
    __syncthreads();
    float4 acc[NUM_CAT];
    #pragma unroll
    for (int c = 0; c < NUM_CAT; ++c) acc[c] = make_float4(0.f, 0.f, 0.f, 0.f);
    const float4* nrow = (const float4*)(nr + (size_t)b * HIS * EMBED);
    for (int h = 0; h < HIS; ++h) {
        float4 v = nrow[h * 192 + tid];
        #pragma unroll
        for (int c = 0; c < NUM_CAT; ++c) {
            float p = plds[c * HIS + h];
            acc[c].x += p * v.x; acc[c].y += p * v.y;
            acc[c].z += p * v.z; acc[c].w += p * v.w;
        }
    }
    const float4* ce = (const float4*)cat_emb;
    float4* oc = (float4*)(out_cat + (size_t)b * NUM_CAT * EMBED);
    #pragma unroll
    for (int c = 0; c < NUM_CAT; ++c) {
        float4 e = ce[c * 192 + tid];
        float4 o;
        o.x = acc[c].x + e.x; o.y = acc[c].y + e.y;
        o.z = acc[c].z + e.z; o.w = acc[c].w + e.w;
        oc[c * 192 + tid] = o;
    }
}

// ---------------- K4c: final logits = cat_repr . w_cat + click ----------------
// one wave per (b,c)
__global__ __launch_bounds__(256) void k4c_logit(
        const float* __restrict__ cat_repr, const float* __restrict__ w_cat,
        const int* __restrict__ cntws, const float* __restrict__ click_emb,
        const float* __restrict__ click_w, const float* __restrict__ click_b,
        float* __restrict__ flogit) {
    int wave = threadIdx.x >> 6, lane = threadIdx.x & 63;
    int w = blockIdx.x * 4 + wave;       // [0,1152)
    int cnt = cntws[w];
    const float* cr = cat_repr + (size_t)w * EMBED;
    float s = 0.f;
    #pragma unroll
    for (int i = 0; i < 12; ++i) {
        int col = lane + i * 64;
        s += cr[col] * w_cat[col];
    }
    if (lane < HIS) {
        const float* ce = click_emb + (size_t)cnt * CLICK_DIM;
        s += ce[lane] * click_w[lane] + ce[lane + HIS] * click_w[lane + HIS];
    }
    #pragma unroll
    for (int off = 32; off; off >>= 1) s += __shfl_down(s, off);
    if (lane == 0)
        flogit[w] = (cnt == 0) ? -INFINITY : (s + click_b[0]);
}

// ---------------- K5: final softmax over C + user_repr ----------------
__global__ __launch_bounds__(256) void k5_user(
        const float* __restrict__ flogit, const float* __restrict__ cat_repr,
        float* __restrict__ user) {
    int b = blockIdx.x, t = threadIdx.x;
    __shared__ float p[NUM_CAT];
    if (t < NUM_CAT) p[t] = flogit[b * NUM_CAT + t];
    __syncthreads();
    float maxv = -INFINITY;
    #pragma unroll
    for (int c = 0; c < NUM_CAT; ++c) maxv = fmaxf(maxv, p[c]);
    float sum = 0.f;
    #pragma unroll
    for (int c = 0; c < NUM_CAT; ++c)
        sum += (p[c] == -INFINITY) ? 0.f : expf(p[c] - maxv);
    float w[NUM_CAT];
    #pragma unroll
    for (int c = 0; c < NUM_CAT; ++c)
        w[c] = (p[c] == -INFINITY) ? 0.f : expf(p[c] - maxv) / sum;
    #pragma unroll
    for (int i = 0; i < 3; ++i) {
        int e = t + i * 256;
        float acc = 0.f;
        #pragma unroll
        for (int c = 0; c < NUM_CAT; ++c)
            acc += w[c] * cat_repr[(size_t)(b * NUM_CAT + c) * EMBED + e];
        user[(size_t)b * EMBED + e] = acc;
    }
}

extern "C" void kernel_launch(void* const* d_in, const int* in_sizes, int n_in,
                              void* d_out, int out_size, void* d_ws, size_t ws_size,
                              hipStream_t stream) {
    const int*   enc    = (const int*)d_in[0];
    const void*  amask  = d_in[1];
    const void*  cmask  = d_in[2];
    const float* wemb   = (const float*)d_in[3];
    const float* projw  = (const float*)d_in[4];
    const float* projb  = (const float*)d_in[5];
    const float* catemb = (const float*)d_in[6];
    const float* wna    = (const float*)d_in[7];
    const float* wca    = (const float*)d_in[8];
    const float* clemb  = (const float*)d_in[9];
    const float* clw    = (const float*)d_in[10];
    const float* clb    = (const float*)d_in[11];

    unsigned char* wsb = (unsigned char*)d_ws;
    __hip_bfloat16* pooled = (__hip_bfloat16*)(wsb + OFF_POOLED);
    __hip_bfloat16* Wt     = (__hip_bfloat16*)(wsb + OFF_WT);
    float* nr      = (float*)(wsb + OFF_NR);
    float* news_w  = (float*)(wsb + OFF_NEWSW);
    float* attn    = (float*)(wsb + OFF_ATTN);
    int*   cnt     = (int*)(wsb + OFF_CNT);
    float* flogit  = (float*)(wsb + OFF_LOGIT);
    int*   flag    = (int*)(wsb + OFF_FLAG);

    float* out_cat = (float*)d_out;
    float* user    = (float*)d_out + BATCH * NUM_CAT * EMBED;

    k0_detect<<<1, 256, 0, stream>>>((const unsigned int*)cmask, flag);
    dim3 gt(24, 24);
    k2a_wt<<<gt, 256, 0, stream>>>(projw, Wt);
    k1_pool<<<3200, 192, 0, stream>>>(enc, amask, wemb, pooled, flag);
    dim3 g2(25, 6);
    k2_mfma<<<g2, 256, 0, stream>>>(pooled, Wt, projb, nr);
    k3_newsw<<<800, 256, 0, stream>>>(nr, wna, news_w);
    k4a_attn<<<288, 256, 0, stream>>>(cmask, news_w, attn, cnt, flag);
    k4b_catrep<<<BATCH, 192, 0, stream>>>(attn, nr, catemb, out_cat);
    k4c_logit<<<288, 256, 0, stream>>>(out_cat, wca, cnt, clemb, clw, clb, flogit);
    k5_user<<<BATCH, 256, 0, stream>>>(flogit, out_cat, user);
}

// Round 4
// 111.889 us; speedup vs baseline: 1.7927x; 1.1551x over previous
//
#include <hip/hip_runtime.h>
#include <hip/hip_bf16.h>
#include <math.h>

#define VOCAB 30522
#define EMBED 768
#define NUM_CAT 18
#define HIS 50
#define SEQ 32
#define BATCH 64
#define CLICK_DIM 100

typedef short v8s __attribute__((ext_vector_type(8)));
typedef float v4f __attribute__((ext_vector_type(4)));

// ---------------- ws layout (byte offsets, 16B aligned) ----------------
#define OFF_POOLED 0            // bf16 [3200][768]           4,915,200 B
#define OFF_WT     4915200      // bf16 [768][768]            1,179,648 B
#define OFF_NR     6094848      // f32  [3200][768]           9,830,400 B
#define OFF_FLAG   16177664     // int (known-good ws address)

// flag: 0 = int32 mask, 1 = uint8 (np.bool_) mask, 2 = float32 mask
__device__ __forceinline__ bool read_mask(const void* p, int i, int flag) {
    if (flag == 0) return ((const int*)p)[i] != 0;
    if (flag == 1) return ((const unsigned char*)p)[i] != 0;
    return ((const float*)p)[i] != 0.0f;
}

__device__ __forceinline__ float dot4(float4 a, float4 b) {
    return a.x * b.x + a.y * b.y + a.z * b.z + a.w * b.w;
}

// ---------------- K0: detect bool layout from category_mask ----------------
__global__ __launch_bounds__(1024) void k0_detect(
        const unsigned int* __restrict__ cm, int* flag_out) {
    __shared__ int word_gt1, byte_gt1;
    if (threadIdx.x == 0) { word_gt1 = 0; byte_gt1 = 0; }
    __syncthreads();
    int lw = 0, lb = 0;
    for (int i = threadIdx.x; i < 14400; i += blockDim.x) {
        unsigned int v = cm[i];
        if (v > 1u) lw = 1;
        if ((v & 0xFFu) > 1u || ((v >> 8) & 0xFFu) > 1u ||
            ((v >> 16) & 0xFFu) > 1u || ((v >> 24) & 0xFFu) > 1u) lb = 1;
    }
    if (lw) atomicOr(&word_gt1, 1);
    if (lb) atomicOr(&byte_gt1, 1);
    __syncthreads();
    if (threadIdx.x == 0) {
        int f = 0;
        if (word_gt1) f = byte_gt1 ? 2 : 1;
        *flag_out = f;
    }
}

// ---------------- K1: gather + masked mean pool -> pooled (bf16) ----------------
// one block per (b,h): 192 threads; masks hoisted to a ballot word; loop is
// pure independent float4 gathers (8 in flight per group)
__global__ __launch_bounds__(192) void k1_pool(
        const int* __restrict__ enc, const void* amask,
        const float* __restrict__ wemb, __hip_bfloat16* __restrict__ pooled,
        const int* __restrict__ flagp) {
    int wave = threadIdx.x >> 6, lane = threadIdx.x & 63;
    int bh = blockIdx.x;                 // [0,3200)
    int flag = *flagp;
    const int* e = enc + bh * SEQ;
    bool m = (lane < SEQ) ? read_mask(amask, bh * SEQ + lane, flag) : false;
    unsigned long long mb = __ballot(m);
    float cnt = (float)__popcll(mb);
    int fslot = wave * 64 + lane;        // float4 index within row [0,192)
    float ax = 0.f, ay = 0.f, az = 0.f, aw = 0.f;
    #pragma unroll
    for (int s0 = 0; s0 < SEQ; s0 += 8) {
        float4 v[8];
        #pragma unroll
        for (int j = 0; j < 8; ++j)
            v[j] = ((const float4*)(wemb + (size_t)e[s0 + j] * EMBED))[fslot];
        #pragma unroll
        for (int j = 0; j < 8; ++j) {
            float mm = ((mb >> (s0 + j)) & 1ull) ? 1.0f : 0.0f;
            ax += mm * v[j].x; ay += mm * v[j].y;
            az += mm * v[j].z; aw += mm * v[j].w;
        }
    }
    float d = 1.0f / fmaxf(cnt, 1.0f);
    union { ushort4 u; unsigned short s[4]; } pk;
    __hip_bfloat16 h0 = __float2bfloat16(ax * d); pk.s[0] = *(unsigned short*)&h0;
    __hip_bfloat16 h1 = __float2bfloat16(ay * d); pk.s[1] = *(unsigned short*)&h1;
    __hip_bfloat16 h2 = __float2bfloat16(az * d); pk.s[2] = *(unsigned short*)&h2;
    __hip_bfloat16 h3 = __float2bfloat16(aw * d); pk.s[3] = *(unsigned short*)&h3;
    *(ushort4*)(pooled + (size_t)bh * EMBED + fslot * 4) = pk.u;
}

// ---------------- K2a: Wt[n][k] = bf16(W[k][n]) ----------------
__global__ __launch_bounds__(256) void k2a_wt(
        const float* __restrict__ W, __hip_bfloat16* __restrict__ Wt) {
    __shared__ float t[32][33];
    int tx = threadIdx.x & 31, ty = threadIdx.x >> 5;   // 32 x 8
    int k0 = blockIdx.x * 32, n0 = blockIdx.y * 32;
    #pragma unroll
    for (int i = 0; i < 4; ++i)
        t[ty + i * 8][tx] = W[(size_t)(k0 + ty + i * 8) * EMBED + n0 + tx];
    __syncthreads();
    #pragma unroll
    for (int i = 0; i < 4; ++i)
        Wt[(size_t)(n0 + ty + i * 8) * EMBED + k0 + tx] =
            __float2bfloat16(t[tx][ty + i * 8]);
}

// ---------------- K2: news_repr = tanh(pooled @ W + b), bf16 MFMA ----------------
#define GBM 128
#define GBK 64
#define LDP 72
__global__ __launch_bounds__(256) void k2_mfma(
        const __hip_bfloat16* __restrict__ A,   // pooled [3200][768]
        const __hip_bfloat16* __restrict__ Bt,  // Wt [768(n)][768(k)]
        const float* __restrict__ bias,
        float* __restrict__ C) {                // news_repr [3200][768]
    __shared__ short As[GBM * LDP];
    __shared__ short Bs[GBM * LDP];
    int tid = threadIdx.x;
    int wave = tid >> 6, lane = tid & 63;
    int l15 = lane & 15, l4 = lane >> 4;
    int wr = wave >> 1, wc = wave & 1;
    int row0 = blockIdx.x * GBM;
    int col0 = blockIdx.y * GBM;
    v4f acc[4][4] = {};

    int r_st[4], c_st[4];
    #pragma unroll
    for (int it = 0; it < 4; ++it) {
        int chunk = tid + it * 256;
        r_st[it] = chunk >> 3; c_st[it] = chunk & 7;
    }

    v8s pa[4], pb[4];
    #pragma unroll
    for (int it = 0; it < 4; ++it) {
        pa[it] = *(const v8s*)(A  + (size_t)(row0 + r_st[it]) * EMBED + c_st[it] * 8);
        pb[it] = *(const v8s*)(Bt + (size_t)(col0 + r_st[it]) * EMBED + c_st[it] * 8);
    }

    for (int s = 0; s < EMBED / GBK; ++s) {
        #pragma unroll
        for (int it = 0; it < 4; ++it) {
            *(v8s*)&As[r_st[it] * LDP + c_st[it] * 8] = pa[it];
            *(v8s*)&Bs[r_st[it] * LDP + c_st[it] * 8] = pb[it];
        }
        __syncthreads();
        if (s < EMBED / GBK - 1) {
            int k0 = (s + 1) * GBK;
            #pragma unroll
            for (int it = 0; it < 4; ++it) {
                pa[it] = *(const v8s*)(A  + (size_t)(row0 + r_st[it]) * EMBED + k0 + c_st[it] * 8);
                pb[it] = *(const v8s*)(Bt + (size_t)(col0 + r_st[it]) * EMBED + k0 + c_st[it] * 8);
            }
        }
        #pragma unroll
        for (int kk = 0; kk < 2; ++kk) {
            v8s af[4], bf_[4];
            #pragma unroll
            for (int mi = 0; mi < 4; ++mi)
                af[mi] = *(const v8s*)&As[(wr * 64 + mi * 16 + l15) * LDP + kk * 32 + l4 * 8];
            #pragma unroll
            for (int ni = 0; ni < 4; ++ni)
                bf_[ni] = *(const v8s*)&Bs[(wc * 64 + ni * 16 + l15) * LDP + kk * 32 + l4 * 8];
            #pragma unroll
            for (int mi = 0; mi < 4; ++mi)
                #pragma unroll
                for (int ni = 0; ni < 4; ++ni)
                    acc[mi][ni] = __builtin_amdgcn_mfma_f32_16x16x32_bf16(
                        af[mi], bf_[ni], acc[mi][ni], 0, 0, 0);
        }
        __syncthreads();
    }
    #pragma unroll
    for (int mi = 0; mi < 4; ++mi) {
        #pragma unroll
        for (int ni = 0; ni < 4; ++ni) {
            int col = col0 + wc * 64 + ni * 16 + l15;
            float b = bias[col];
            #pragma unroll
            for (int r = 0; r < 4; ++r) {
                int row = row0 + wr * 64 + mi * 16 + l4 * 4 + r;
                C[(size_t)row * EMBED + col] = tanhf(acc[mi][ni][r] + b);
            }
        }
    }
}

// ---------------- K4: fused news_w + cat softmax + einsum + logits + user ----------------
// one block per b, 256 threads (4 waves; threads 0..191 own a float4 col slot)
__global__ __launch_bounds__(256) void k4_fused(
        const void* cmask, const float* __restrict__ nr,
        const float* __restrict__ wna, const float* __restrict__ cat_emb,
        const float* __restrict__ w_cat, const float* __restrict__ click_emb,
        const float* __restrict__ click_w, const float* __restrict__ click_b,
        float* __restrict__ out_cat, float* __restrict__ user,
        const int* __restrict__ flagp) {
    int b = blockIdx.x, tid = threadIdx.x;
    int wave = tid >> 6, lane = tid & 63;
    int flag = *flagp;
    __shared__ float nwlds[HIS];
    __shared__ float plds[NUM_CAT][HIS];
    __shared__ float redbuf[NUM_CAT][3];
    __shared__ float clicks[NUM_CAT];
    __shared__ int   cnts[NUM_CAT];
    __shared__ float logit[NUM_CAT];

    const float4* nrb = (const float4*)(nr + (size_t)b * HIS * EMBED);
    const float4* wna4 = (const float4*)wna;

    // ---- phase 0: news_w[h] for this b (nr[b] first pass; warms L2) ----
    float4 wn0 = wna4[lane], wn1 = wna4[lane + 64], wn2 = wna4[lane + 128];
    for (int h = wave; h < HIS; h += 4) {
        const float4* row = nrb + h * 192;
        float s = dot4(row[lane], wn0) + dot4(row[lane + 64], wn1)
                + dot4(row[lane + 128], wn2);
        #pragma unroll
        for (int off = 32; off; off >>= 1) s += __shfl_down(s, off);
        if (lane == 0) nwlds[h] = s;
    }
    __syncthreads();

    // ---- phase 1: per-cat masked softmax + click score ----
    for (int c = wave; c < NUM_CAT; c += 4) {
        bool m = false; float v = -INFINITY;
        if (lane < HIS) {
            m = read_mask(cmask, (b * NUM_CAT + c) * HIS + lane, flag);
            if (m) v = nwlds[lane];
        }
        unsigned long long bal = __ballot(m);
        int cnt = __popcll(bal);
        float maxv = v;
        #pragma unroll
        for (int off = 32; off; off >>= 1) maxv = fmaxf(maxv, __shfl_xor(maxv, off));
        float e = (v == -INFINITY) ? 0.f : expf(v - maxv);
        float sum = e;
        #pragma unroll
        for (int off = 32; off; off >>= 1) sum += __shfl_xor(sum, off);
        if (lane < HIS)
            plds[c][lane] = (cnt == 0 || v == -INFINITY) ? 0.f : e / sum;
        // click score: lanes 0..49, two elems each
        float cs = 0.f;
        if (lane < HIS) {
            const float* ce = click_emb + (size_t)cnt * CLICK_DIM;
            cs = ce[lane] * click_w[lane] + ce[lane + HIS] * click_w[lane + HIS];
        }
        #pragma unroll
        for (int off = 32; off; off >>= 1) cs += __shfl_down(cs, off);
        if (lane == 0) { cnts[c] = cnt; clicks[c] = cs + click_b[0]; }
    }
    __syncthreads();

    // ---- phase 2: einsum (nr[b] second pass, L2-hot) + cat_emb + catw dot ----
    float4 acc[NUM_CAT];
    float part[NUM_CAT];
    if (tid < 192) {
        #pragma unroll
        for (int c = 0; c < NUM_CAT; ++c) acc[c] = make_float4(0.f, 0.f, 0.f, 0.f);
        for (int h = 0; h < HIS; ++h) {
            float4 v = nrb[h * 192 + tid];
            #pragma unroll
            for (int c = 0; c < NUM_CAT; ++c) {
                float p = plds[c][h];
                acc[c].x += p * v.x; acc[c].y += p * v.y;
                acc[c].z += p * v.z; acc[c].w += p * v.w;
            }
        }
        const float4* ce4 = (const float4*)cat_emb;
        float4* oc4 = (float4*)(out_cat + (size_t)b * NUM_CAT * EMBED);
        float4 wv = ((const float4*)w_cat)[tid];
        #pragma unroll
        for (int c = 0; c < NUM_CAT; ++c) {
            float4 e = ce4[c * 192 + tid];
            acc[c].x += e.x; acc[c].y += e.y; acc[c].z += e.z; acc[c].w += e.w;
            oc4[c * 192 + tid] = acc[c];
            part[c] = dot4(acc[c], wv);
        }
    } else {
        #pragma unroll
        for (int c = 0; c < NUM_CAT; ++c) part[c] = 0.f;
    }
    // block reduce part[c] over waves 0..2
    #pragma unroll
    for (int c = 0; c < NUM_CAT; ++c) {
        float s = part[c];
        #pragma unroll
        for (int off = 32; off; off >>= 1) s += __shfl_down(s, off);
        if (lane == 0 && wave < 3) redbuf[c][wave] = s;
    }
    __syncthreads();
    if (tid < NUM_CAT) {
        float catw = redbuf[tid][0] + redbuf[tid][1] + redbuf[tid][2];
        logit[tid] = (cnts[tid] == 0) ? -INFINITY : (catw + clicks[tid]);
    }
    __syncthreads();

    // ---- phase 3: softmax over C (redundant per thread) + user_repr ----
    if (tid < 192) {
        float maxv = -INFINITY;
        #pragma unroll
        for (int c = 0; c < NUM_CAT; ++c) maxv = fmaxf(maxv, logit[c]);
        float sum = 0.f;
        #pragma unroll
        for (int c = 0; c < NUM_CAT; ++c)
            sum += (logit[c] == -INFINITY) ? 0.f : expf(logit[c] - maxv);
        float4 u = make_float4(0.f, 0.f, 0.f, 0.f);
        #pragma unroll
        for (int c = 0; c < NUM_CAT; ++c) {
            float w = (logit[c] == -INFINITY) ? 0.f : expf(logit[c] - maxv) / sum;
            u.x += w * acc[c].x; u.y += w * acc[c].y;
            u.z += w * acc[c].z; u.w += w * acc[c].w;
        }
        ((float4*)(user + (size_t)b * EMBED))[tid] = u;
    }
}

extern "C" void kernel_launch(void* const* d_in, const int* in_sizes, int n_in,
                              void* d_out, int out_size, void* d_ws, size_t ws_size,
                              hipStream_t stream) {
    const int*   enc    = (const int*)d_in[0];
    const void*  amask  = d_in[1];
    const void*  cmask  = d_in[2];
    const float* wemb   = (const float*)d_in[3];
    const float* projw  = (const float*)d_in[4];
    const float* projb  = (const float*)d_in[5];
    const float* catemb = (const float*)d_in[6];
    const float* wna    = (const float*)d_in[7];
    const float* wca    = (const float*)d_in[8];
    const float* clemb  = (const float*)d_in[9];
    const float* clw    = (const float*)d_in[10];
    const float* clb    = (const float*)d_in[11];

    unsigned char* wsb = (unsigned char*)d_ws;
    __hip_bfloat16* pooled = (__hip_bfloat16*)(wsb + OFF_POOLED);
    __hip_bfloat16* Wt     = (__hip_bfloat16*)(wsb + OFF_WT);
    float* nr   = (float*)(wsb + OFF_NR);
    int*   flag = (int*)(wsb + OFF_FLAG);

    float* out_cat = (float*)d_out;
    float* user    = (float*)d_out + BATCH * NUM_CAT * EMBED;

    k0_detect<<<1, 1024, 0, stream>>>((const unsigned int*)cmask, flag);
    dim3 gt(24, 24);
    k2a_wt<<<gt, 256, 0, stream>>>(projw, Wt);
    k1_pool<<<3200, 192, 0, stream>>>(enc, amask, wemb, pooled, flag);
    dim3 g2(25, 6);
    k2_mfma<<<g2, 256, 0, stream>>>(pooled, Wt, projb, nr);
    k4_fused<<<BATCH, 256, 0, stream>>>(cmask, nr, wna, catemb, wca,
                                        clemb, clw, clb, out_cat, user, flag);
}

// Round 5
// 104.975 us; speedup vs baseline: 1.9107x; 1.0659x over previous
//
#include <hip/hip_runtime.h>
#include <hip/hip_bf16.h>
#include <math.h>

#define VOCAB 30522
#define EMBED 768
#define NUM_CAT 18
#define HIS 50
#define SEQ 32
#define BATCH 64
#define CLICK_DIM 100

typedef short v8s __attribute__((ext_vector_type(8)));
typedef float v4f __attribute__((ext_vector_type(4)));

// ---------------- ws layout (byte offsets, 16B aligned) ----------------
#define OFF_POOLED 0            // bf16 [3200][768]           4,915,200 B
#define OFF_WT     4915200      // bf16 [768][768]            1,179,648 B
#define OFF_NR     6094848      // f32  [3200][768]           9,830,400 B
#define OFF_FLAG   16177664     // int
#define OFF_WTAB   16252928     // bf16 [30522][768]         46,881,792 B
#define WS_NEED    63134720ull  // OFF_WTAB + 46,881,792

// flag: 0 = int32 mask, 1 = uint8 (np.bool_) mask, 2 = float32 mask
__device__ __forceinline__ bool read_mask(const void* p, int i, int flag) {
    if (flag == 0) return ((const int*)p)[i] != 0;
    if (flag == 1) return ((const unsigned char*)p)[i] != 0;
    return ((const float*)p)[i] != 0.0f;
}

__device__ __forceinline__ float dot4(float4 a, float4 b) {
    return a.x * b.x + a.y * b.y + a.z * b.z + a.w * b.w;
}

__device__ __forceinline__ float bf2f(unsigned short u) {
    union { unsigned int i; float f; } cv;
    cv.i = ((unsigned int)u) << 16;
    return cv.f;
}
__device__ __forceinline__ unsigned short f2bf(float f) {
    __hip_bfloat16 h = __float2bfloat16(f);
    return *(unsigned short*)&h;
}

// ---------------- KPREP: fused Wt transpose + mask detect + wemb->bf16 ----------------
// blocks [0,576): transpose; block 576: detect; blocks [577, 577+2048): convert
#define CONV_BLOCKS 2048
__global__ __launch_bounds__(256) void kprep(
        const float* __restrict__ W, __hip_bfloat16* __restrict__ Wt,
        const unsigned int* __restrict__ cm, int* __restrict__ flag_out,
        const float* __restrict__ wemb, unsigned short* __restrict__ wtab) {
    int blk = blockIdx.x;
    if (blk < 576) {
        // ---- Wt[n][k] = bf16(W[k][n]) ----
        __shared__ float t[32][33];
        int tx = threadIdx.x & 31, ty = threadIdx.x >> 5;   // 32 x 8
        int k0 = (blk % 24) * 32, n0 = (blk / 24) * 32;
        #pragma unroll
        for (int i = 0; i < 4; ++i)
            t[ty + i * 8][tx] = W[(size_t)(k0 + ty + i * 8) * EMBED + n0 + tx];
        __syncthreads();
        #pragma unroll
        for (int i = 0; i < 4; ++i)
            Wt[(size_t)(n0 + ty + i * 8) * EMBED + k0 + tx] =
                __float2bfloat16(t[tx][ty + i * 8]);
    } else if (blk == 576) {
        // ---- mask layout detect ----
        __shared__ int word_gt1, byte_gt1;
        if (threadIdx.x == 0) { word_gt1 = 0; byte_gt1 = 0; }
        __syncthreads();
        int lw = 0, lb = 0;
        for (int i = threadIdx.x; i < 14400; i += 256) {
            unsigned int v = cm[i];
            if (v > 1u) lw = 1;
            if ((v & 0xFFu) > 1u || ((v >> 8) & 0xFFu) > 1u ||
                ((v >> 16) & 0xFFu) > 1u || ((v >> 24) & 0xFFu) > 1u) lb = 1;
        }
        if (lw) atomicOr(&word_gt1, 1);
        if (lb) atomicOr(&byte_gt1, 1);
        __syncthreads();
        if (threadIdx.x == 0) {
            int f = 0;
            if (word_gt1) f = byte_gt1 ? 2 : 1;
            *flag_out = f;
        }
    } else {
        // ---- wtab = bf16(wemb), streaming ----
        const int N4 = (VOCAB * EMBED) / 4;           // 5,860,224 float4
        int gtid = (blk - 577) * 256 + threadIdx.x;   // [0, 524288)
        const float4* src = (const float4*)wemb;
        ushort4* dst = (ushort4*)wtab;
        for (int i = gtid; i < N4; i += CONV_BLOCKS * 256) {
            float4 v = src[i];
            ushort4 o;
            o.x = f2bf(v.x); o.y = f2bf(v.y); o.z = f2bf(v.z); o.w = f2bf(v.w);
            dst[i] = o;
        }
    }
}

// ---------------- K1B: gather (bf16 table) + masked mean pool ----------------
// one block per (b,h): 192 threads; thread owns 4 bf16 cols (8B/lane loads)
__global__ __launch_bounds__(192) void k1b_pool(
        const int* __restrict__ enc, const void* amask,
        const unsigned short* __restrict__ wtab, __hip_bfloat16* __restrict__ pooled,
        const int* __restrict__ flagp) {
    int wave = threadIdx.x >> 6, lane = threadIdx.x & 63;
    int bh = blockIdx.x;                 // [0,3200)
    int flag = *flagp;
    const int* e = enc + bh * SEQ;
    bool m = (lane < SEQ) ? read_mask(amask, bh * SEQ + lane, flag) : false;
    unsigned long long mb = __ballot(m);
    float cnt = (float)__popcll(mb);
    int fslot = wave * 64 + lane;        // ushort4 index within row [0,192)
    float ax = 0.f, ay = 0.f, az = 0.f, aw = 0.f;
    #pragma unroll
    for (int s0 = 0; s0 < SEQ; s0 += 8) {
        ushort4 v[8];
        #pragma unroll
        for (int j = 0; j < 8; ++j)
            v[j] = ((const ushort4*)(wtab + (size_t)e[s0 + j] * EMBED))[fslot];
        #pragma unroll
        for (int j = 0; j < 8; ++j) {
            float mm = ((mb >> (s0 + j)) & 1ull) ? 1.0f : 0.0f;
            ax += mm * bf2f(v[j].x); ay += mm * bf2f(v[j].y);
            az += mm * bf2f(v[j].z); aw += mm * bf2f(v[j].w);
        }
    }
    float d = 1.0f / fmaxf(cnt, 1.0f);
    ushort4 pk;
    pk.x = f2bf(ax * d); pk.y = f2bf(ay * d);
    pk.z = f2bf(az * d); pk.w = f2bf(aw * d);
    *(ushort4*)((unsigned short*)pooled + (size_t)bh * EMBED + fslot * 4) = pk;
}

// ---------------- fallback path kernels (ws too small) ----------------
__global__ __launch_bounds__(1024) void k0_detect(
        const unsigned int* __restrict__ cm, int* flag_out) {
    __shared__ int word_gt1, byte_gt1;
    if (threadIdx.x == 0) { word_gt1 = 0; byte_gt1 = 0; }
    __syncthreads();
    int lw = 0, lb = 0;
    for (int i = threadIdx.x; i < 14400; i += blockDim.x) {
        unsigned int v = cm[i];
        if (v > 1u) lw = 1;
        if ((v & 0xFFu) > 1u || ((v >> 8) & 0xFFu) > 1u ||
            ((v >> 16) & 0xFFu) > 1u || ((v >> 24) & 0xFFu) > 1u) lb = 1;
    }
    if (lw) atomicOr(&word_gt1, 1);
    if (lb) atomicOr(&byte_gt1, 1);
    __syncthreads();
    if (threadIdx.x == 0) {
        int f = 0;
        if (word_gt1) f = byte_gt1 ? 2 : 1;
        *flag_out = f;
    }
}

__global__ __launch_bounds__(256) void k2a_wt(
        const float* __restrict__ W, __hip_bfloat16* __restrict__ Wt) {
    __shared__ float t[32][33];
    int tx = threadIdx.x & 31, ty = threadIdx.x >> 5;
    int k0 = blockIdx.x * 32, n0 = blockIdx.y * 32;
    #pragma unroll
    for (int i = 0; i < 4; ++i)
        t[ty + i * 8][tx] = W[(size_t)(k0 + ty + i * 8) * EMBED + n0 + tx];
    __syncthreads();
    #pragma unroll
    for (int i = 0; i < 4; ++i)
        Wt[(size_t)(n0 + ty + i * 8) * EMBED + k0 + tx] =
            __float2bfloat16(t[tx][ty + i * 8]);
}

__global__ __launch_bounds__(192) void k1_pool(
        const int* __restrict__ enc, const void* amask,
        const float* __restrict__ wemb, __hip_bfloat16* __restrict__ pooled,
        const int* __restrict__ flagp) {
    int wave = threadIdx.x >> 6, lane = threadIdx.x & 63;
    int bh = blockIdx.x;
    int flag = *flagp;
    const int* e = enc + bh * SEQ;
    bool m = (lane < SEQ) ? read_mask(amask, bh * SEQ + lane, flag) : false;
    unsigned long long mb = __ballot(m);
    float cnt = (float)__popcll(mb);
    int fslot = wave * 64 + lane;
    float ax = 0.f, ay = 0.f, az = 0.f, aw = 0.f;
    #pragma unroll
    for (int s0 = 0; s0 < SEQ; s0 += 8) {
        float4 v[8];
        #pragma unroll
        for (int j = 0; j < 8; ++j)
            v[j] = ((const float4*)(wemb + (size_t)e[s0 + j] * EMBED))[fslot];
        #pragma unroll
        for (int j = 0; j < 8; ++j) {
            float mm = ((mb >> (s0 + j)) & 1ull) ? 1.0f : 0.0f;
            ax += mm * v[j].x; ay += mm * v[j].y;
            az += mm * v[j].z; aw += mm * v[j].w;
        }
    }
    float d = 1.0f / fmaxf(cnt, 1.0f);
    ushort4 pk;
    pk.x = f2bf(ax * d); pk.y = f2bf(ay * d);
    pk.z = f2bf(az * d); pk.w = f2bf(aw * d);
    *(ushort4*)((unsigned short*)pooled + (size_t)bh * EMBED + fslot * 4) = pk;
}

// ---------------- K2: news_repr = tanh(pooled @ W + b), bf16 MFMA ----------------
#define GBM 128
#define GBK 64
#define LDP 72
__global__ __launch_bounds__(256) void k2_mfma(
        const __hip_bfloat16* __restrict__ A,   // pooled [3200][768]
        const __hip_bfloat16* __restrict__ Bt,  // Wt [768(n)][768(k)]
        const float* __restrict__ bias,
        float* __restrict__ C) {                // news_repr [3200][768]
    __shared__ short As[GBM * LDP];
    __shared__ short Bs[GBM * LDP];
    int tid = threadIdx.x;
    int wave = tid >> 6, lane = tid & 63;
    int l15 = lane & 15, l4 = lane >> 4;
    int wr = wave >> 1, wc = wave & 1;
    int row0 = blockIdx.x * GBM;
    int col0 = blockIdx.y * GBM;
    v4f acc[4][4] = {};

    int r_st[4], c_st[4];
    #pragma unroll
    for (int it = 0; it < 4; ++it) {
        int chunk = tid + it * 256;
        r_st[it] = chunk >> 3; c_st[it] = chunk & 7;
    }

    v8s pa[4], pb[4];
    #pragma unroll
    for (int it = 0; it < 4; ++it) {
        pa[it] = *(const v8s*)(A  + (size_t)(row0 + r_st[it]) * EMBED + c_st[it] * 8);
        pb[it] = *(const v8s*)(Bt + (size_t)(col0 + r_st[it]) * EMBED + c_st[it] * 8);
    }

    for (int s = 0; s < EMBED / GBK; ++s) {
        #pragma unroll
        for (int it = 0; it < 4; ++it) {
            *(v8s*)&As[r_st[it] * LDP + c_st[it] * 8] = pa[it];
            *(v8s*)&Bs[r_st[it] * LDP + c_st[it] * 8] = pb[it];
        }
        __syncthreads();
        if (s < EMBED / GBK - 1) {
            int k0 = (s + 1) * GBK;
            #pragma unroll
            for (int it = 0; it < 4; ++it) {
                pa[it] = *(const v8s*)(A  + (size_t)(row0 + r_st[it]) * EMBED + k0 + c_st[it] * 8);
                pb[it] = *(const v8s*)(Bt + (size_t)(col0 + r_st[it]) * EMBED + k0 + c_st[it] * 8);
            }
        }
        #pragma unroll
        for (int kk = 0; kk < 2; ++kk) {
            v8s af[4], bf_[4];
            #pragma unroll
            for (int mi = 0; mi < 4; ++mi)
                af[mi] = *(const v8s*)&As[(wr * 64 + mi * 16 + l15) * LDP + kk * 32 + l4 * 8];
            #pragma unroll
            for (int ni = 0; ni < 4; ++ni)
                bf_[ni] = *(const v8s*)&Bs[(wc * 64 + ni * 16 + l15) * LDP + kk * 32 + l4 * 8];
            #pragma unroll
            for (int mi = 0; mi < 4; ++mi)
                #pragma unroll
                for (int ni = 0; ni < 4; ++ni)
                    acc[mi][ni] = __builtin_amdgcn_mfma_f32_16x16x32_bf16(
                        af[mi], bf_[ni], acc[mi][ni], 0, 0, 0);
        }
        __syncthreads();
    }
    #pragma unroll
    for (int mi = 0; mi < 4; ++mi) {
        #pragma unroll
        for (int ni = 0; ni < 4; ++ni) {
            int col = col0 + wc * 64 + ni * 16 + l15;
            float b = bias[col];
            #pragma unroll
            for (int r = 0; r < 4; ++r) {
                int row = row0 + wr * 64 + mi * 16 + l4 * 4 + r;
                C[(size_t)row * EMBED + col] = tanhf(acc[mi][ni][r] + b);
            }
        }
    }
}

// ---------------- K4: fused news_w + cat softmax + einsum + logits + user ----------------
__global__ __launch_bounds__(256) void k4_fused(
        const void* cmask, const float* __restrict__ nr,
        const float* __restrict__ wna, const float* __restrict__ cat_emb,
        const float* __restrict__ w_cat, const float* __restrict__ click_emb,
        const float* __restrict__ click_w, const float* __restrict__ click_b,
        float* __restrict__ out_cat, float* __restrict__ user,
        const int* __restrict__ flagp) {
    int b = blockIdx.x, tid = threadIdx.x;
    int wave = tid >> 6, lane = tid & 63;
    int flag = *flagp;
    __shared__ float nwlds[HIS];
    __shared__ float plds[NUM_CAT][HIS];
    __shared__ float redbuf[NUM_CAT][3];
    __shared__ float clicks[NUM_CAT];
    __shared__ int   cnts[NUM_CAT];
    __shared__ float logit[NUM_CAT];

    const float4* nrb = (const float4*)(nr + (size_t)b * HIS * EMBED);
    const float4* wna4 = (const float4*)wna;

    // ---- phase 0: news_w[h] ----
    float4 wn0 = wna4[lane], wn1 = wna4[lane + 64], wn2 = wna4[lane + 128];
    for (int h = wave; h < HIS; h += 4) {
        const float4* row = nrb + h * 192;
        float s = dot4(row[lane], wn0) + dot4(row[lane + 64], wn1)
                + dot4(row[lane + 128], wn2);
        #pragma unroll
        for (int off = 32; off; off >>= 1) s += __shfl_down(s, off);
        if (lane == 0) nwlds[h] = s;
    }
    __syncthreads();

    // ---- phase 1: per-cat masked softmax + click score ----
    for (int c = wave; c < NUM_CAT; c += 4) {
        bool m = false; float v = -INFINITY;
        if (lane < HIS) {
            m = read_mask(cmask, (b * NUM_CAT + c) * HIS + lane, flag);
            if (m) v = nwlds[lane];
        }
        unsigned long long bal = __ballot(m);
        int cnt = __popcll(bal);
        float maxv = v;
        #pragma unroll
        for (int off = 32; off; off >>= 1) maxv = fmaxf(maxv, __shfl_xor(maxv, off));
        float e = (v == -INFINITY) ? 0.f : expf(v - maxv);
        float sum = e;
        #pragma unroll
        for (int off = 32; off; off >>= 1) sum += __shfl_xor(sum, off);
        if (lane < HIS)
            plds[c][lane] = (cnt == 0 || v == -INFINITY) ? 0.f : e / sum;
        float cs = 0.f;
        if (lane < HIS) {
            const float* ce = click_emb + (size_t)cnt * CLICK_DIM;
            cs = ce[lane] * click_w[lane] + ce[lane + HIS] * click_w[lane + HIS];
        }
        #pragma unroll
        for (int off = 32; off; off >>= 1) cs += __shfl_down(cs, off);
        if (lane == 0) { cnts[c] = cnt; clicks[c] = cs + click_b[0]; }
    }
    __syncthreads();

    // ---- phase 2: einsum + cat_emb + catw dot ----
    float4 acc[NUM_CAT];
    float part[NUM_CAT];
    if (tid < 192) {
        #pragma unroll
        for (int c = 0; c < NUM_CAT; ++c) acc[c] = make_float4(0.f, 0.f, 0.f, 0.f);
        for (int h = 0; h < HIS; ++h) {
            float4 v = nrb[h * 192 + tid];
            #pragma unroll
            for (int c = 0; c < NUM_CAT; ++c) {
                float p = plds[c][h];
                acc[c].x += p * v.x; acc[c].y += p * v.y;
                acc[c].z += p * v.z; acc[c].w += p * v.w;
            }
        }
        const float4* ce4 = (const float4*)cat_emb;
        float4* oc4 = (float4*)(out_cat + (size_t)b * NUM_CAT * EMBED);
        float4 wv = ((const float4*)w_cat)[tid];
        #pragma unroll
        for (int c = 0; c < NUM_CAT; ++c) {
            float4 e = ce4[c * 192 + tid];
            acc[c].x += e.x; acc[c].y += e.y; acc[c].z += e.z; acc[c].w += e.w;
            oc4[c * 192 + tid] = acc[c];
            part[c] = dot4(acc[c], wv);
        }
    } else {
        #pragma unroll
        for (int c = 0; c < NUM_CAT; ++c) part[c] = 0.f;
    }
    #pragma unroll
    for (int c = 0; c < NUM_CAT; ++c) {
        float s = part[c];
        #pragma unroll
        for (int off = 32; off; off >>= 1) s += __shfl_down(s, off);
        if (lane == 0 && wave < 3) redbuf[c][wave] = s;
    }
    __syncthreads();
    if (tid < NUM_CAT) {
        float catw = redbuf[tid][0] + redbuf[tid][1] + redbuf[tid][2];
        logit[tid] = (cnts[tid] == 0) ? -INFINITY : (catw + clicks[tid]);
    }
    __syncthreads();

    // ---- phase 3: softmax over C + user_repr ----
    if (tid < 192) {
        float maxv = -INFINITY;
        #pragma unroll
        for (int c = 0; c < NUM_CAT; ++c) maxv = fmaxf(maxv, logit[c]);
        float sum = 0.f;
        #pragma unroll
        for (int c = 0; c < NUM_CAT; ++c)
            sum += (logit[c] == -INFINITY) ? 0.f : expf(logit[c] - maxv);
        float4 u = make_float4(0.f, 0.f, 0.f, 0.f);
        #pragma unroll
        for (int c = 0; c < NUM_CAT; ++c) {
            float w = (logit[c] == -INFINITY) ? 0.f : expf(logit[c] - maxv) / sum;
            u.x += w * acc[c].x; u.y += w * acc[c].y;
            u.z += w * acc[c].z; u.w += w * acc[c].w;
        }
        ((float4*)(user + (size_t)b * EMBED))[tid] = u;
    }
}

extern "C" void kernel_launch(void* const* d_in, const int* in_sizes, int n_in,
                              void* d_out, int out_size, void* d_ws, size_t ws_size,
                              hipStream_t stream) {
    const int*   enc    = (const int*)d_in[0];
    const void*  amask  = d_in[1];
    const void*  cmask  = d_in[2];
    const float* wemb   = (const float*)d_in[3];
    const float* projw  = (const float*)d_in[4];
    const float* projb  = (const float*)d_in[5];
    const float* catemb = (const float*)d_in[6];
    const float* wna    = (const float*)d_in[7];
    const float* wca    = (const float*)d_in[8];
    const float* clemb  = (const float*)d_in[9];
    const float* clw    = (const float*)d_in[10];
    const float* clb    = (const float*)d_in[11];

    unsigned char* wsb = (unsigned char*)d_ws;
    __hip_bfloat16* pooled = (__hip_bfloat16*)(wsb + OFF_POOLED);
    __hip_bfloat16* Wt     = (__hip_bfloat16*)(wsb + OFF_WT);
    float* nr   = (float*)(wsb + OFF_NR);
    int*   flag = (int*)(wsb + OFF_FLAG);
    unsigned short* wtab = (unsigned short*)(wsb + OFF_WTAB);

    float* out_cat = (float*)d_out;
    float* user    = (float*)d_out + BATCH * NUM_CAT * EMBED;

    if (ws_size >= WS_NEED) {
        kprep<<<577 + CONV_BLOCKS, 256, 0, stream>>>(
            projw, Wt, (const unsigned int*)cmask, flag, wemb, wtab);
        k1b_pool<<<3200, 192, 0, stream>>>(enc, amask, wtab, pooled, flag);
    } else {
        k0_detect<<<1, 1024, 0, stream>>>((const unsigned int*)cmask, flag);
        dim3 gt(24, 24);
        k2a_wt<<<gt, 256, 0, stream>>>(projw, Wt);
        k1_pool<<<3200, 192, 0, stream>>>(enc, amask, wemb, pooled, flag);
    }
    dim3 g2(25, 6);
    k2_mfma<<<g2, 256, 0, stream>>>(pooled, Wt, projb, nr);
    k4_fused<<<BATCH, 256, 0, stream>>>(cmask, nr, wna, catemb, wca,
                                        clemb, clw, clb, out_cat, user, flag);
}

// Round 6
// 94.565 us; speedup vs baseline: 2.1211x; 1.1101x over previous
//
#include <hip/hip_runtime.h>
#include <hip/hip_bf16.h>
#include <math.h>

#define VOCAB 30522
#define EMBED 768
#define NUM_CAT 18
#define HIS 50
#define SEQ 32
#define BATCH 64
#define CLICK_DIM 100

typedef short v8s __attribute__((ext_vector_type(8)));
typedef float v4f __attribute__((ext_vector_type(4)));
typedef unsigned short v8u __attribute__((ext_vector_type(8)));

// ---------------- ws layout (byte offsets, 16B aligned) ----------------
#define OFF_POOLED 0            // bf16 [3200][768]           4,915,200 B
#define OFF_WT     4915200      // bf16 [768][768]            1,179,648 B
#define OFF_NR     6094848      // f32  [3200][768]           9,830,400 B
#define OFF_NEWSW  15925248     // f32  [3200]                   12,800 B
#define OFF_FLAG   16177664     // int
#define OFF_WTAB   16252928     // bf16 [30522][768]         46,881,792 B
#define WS_NEED    63134720ull

// flag: 0 = int32 mask, 1 = uint8 (np.bool_) mask, 2 = float32 mask
__device__ __forceinline__ bool read_mask(const void* p, int i, int flag) {
    if (flag == 0) return ((const int*)p)[i] != 0;
    if (flag == 1) return ((const unsigned char*)p)[i] != 0;
    return ((const float*)p)[i] != 0.0f;
}

__device__ __forceinline__ float bf2f(unsigned short u) {
    union { unsigned int i; float f; } cv;
    cv.i = ((unsigned int)u) << 16;
    return cv.f;
}
__device__ __forceinline__ unsigned short f2bf(float f) {
    __hip_bfloat16 h = __float2bfloat16(f);
    return *(unsigned short*)&h;
}

// ---------------- KPREP: Wt transpose + mask detect + news_w zero + wemb->bf16 ----------------
#define CONV_BLOCKS 2048
__global__ __launch_bounds__(256) void kprep(
        const float* __restrict__ W, __hip_bfloat16* __restrict__ Wt,
        const unsigned int* __restrict__ cm, int* __restrict__ flag_out,
        const float* __restrict__ wemb, unsigned short* __restrict__ wtab,
        float* __restrict__ news_w) {
    int blk = blockIdx.x;
    if (blk < 576) {
        __shared__ float t[32][33];
        int tx = threadIdx.x & 31, ty = threadIdx.x >> 5;
        int k0 = (blk % 24) * 32, n0 = (blk / 24) * 32;
        #pragma unroll
        for (int i = 0; i < 4; ++i)
            t[ty + i * 8][tx] = W[(size_t)(k0 + ty + i * 8) * EMBED + n0 + tx];
        __syncthreads();
        #pragma unroll
        for (int i = 0; i < 4; ++i)
            Wt[(size_t)(n0 + ty + i * 8) * EMBED + k0 + tx] =
                __float2bfloat16(t[tx][ty + i * 8]);
    } else if (blk == 576) {
        __shared__ int word_gt1, byte_gt1;
        if (threadIdx.x == 0) { word_gt1 = 0; byte_gt1 = 0; }
        __syncthreads();
        int lw = 0, lb = 0;
        for (int i = threadIdx.x; i < 14400; i += 256) {
            unsigned int v = cm[i];
            if (v > 1u) lw = 1;
            if ((v & 0xFFu) > 1u || ((v >> 8) & 0xFFu) > 1u ||
                ((v >> 16) & 0xFFu) > 1u || ((v >> 24) & 0xFFu) > 1u) lb = 1;
        }
        if (lw) atomicOr(&word_gt1, 1);
        if (lb) atomicOr(&byte_gt1, 1);
        // zero news_w (accumulated via atomics by k2)
        for (int i = threadIdx.x; i < BATCH * HIS; i += 256) news_w[i] = 0.f;
        __syncthreads();
        if (threadIdx.x == 0) {
            int f = 0;
            if (word_gt1) f = byte_gt1 ? 2 : 1;
            *flag_out = f;
        }
    } else {
        const int N4 = (VOCAB * EMBED) / 4;
        int gtid = (blk - 577) * 256 + threadIdx.x;
        const float4* src = (const float4*)wemb;
        ushort4* dst = (ushort4*)wtab;
        for (int i = gtid; i < N4; i += CONV_BLOCKS * 256) {
            float4 v = src[i];
            ushort4 o;
            o.x = f2bf(v.x); o.y = f2bf(v.y); o.z = f2bf(v.z); o.w = f2bf(v.w);
            dst[i] = o;
        }
    }
}

// ---------------- K1B: gather (bf16 table) + masked mean pool ----------------
// 2 rows per block, 192 threads; thread owns ushort8 (16B) slot: 96 slots/row
__global__ __launch_bounds__(192) void k1b_pool(
        const int* __restrict__ enc, const void* amask,
        const unsigned short* __restrict__ wtab, __hip_bfloat16* __restrict__ pooled,
        const int* __restrict__ flagp) {
    int tid = threadIdx.x, lane = tid & 63;
    int blk = blockIdx.x;                // [0,1600)
    int flag = *flagp;
    int bh0 = blk * 2, bh1 = blk * 2 + 1;
    bool mm = (lane < 32) ? read_mask(amask, bh0 * SEQ + lane, flag)
                          : read_mask(amask, bh1 * SEQ + (lane - 32), flag);
    unsigned long long bal = __ballot(mm);
    unsigned int mb0 = (unsigned int)(bal & 0xFFFFFFFFull);
    unsigned int mb1 = (unsigned int)(bal >> 32);
    int half = (tid >= 96) ? 1 : 0;
    int bh = half ? bh1 : bh0;
    unsigned int mb = half ? mb1 : mb0;
    float cnt = (float)__popc(mb);
    int slot = tid - half * 96;          // [0,96)
    const int* e = enc + bh * SEQ;
    float a[8] = {};
    #pragma unroll
    for (int s0 = 0; s0 < SEQ; s0 += 8) {
        v8u v[8];
        #pragma unroll
        for (int j = 0; j < 8; ++j)
            v[j] = ((const v8u*)(wtab + (size_t)e[s0 + j] * EMBED))[slot];
        #pragma unroll
        for (int j = 0; j < 8; ++j) {
            float m = ((mb >> (s0 + j)) & 1u) ? 1.0f : 0.0f;
            #pragma unroll
            for (int k = 0; k < 8; ++k) a[k] += m * bf2f(v[j][k]);
        }
    }
    float d = 1.0f / fmaxf(cnt, 1.0f);
    v8u o;
    #pragma unroll
    for (int k = 0; k < 8; ++k) o[k] = f2bf(a[k] * d);
    *(v8u*)(((unsigned short*)pooled) + (size_t)bh * EMBED + slot * 8) = o;
}

// ---------------- fallback path (ws too small) ----------------
__global__ __launch_bounds__(1024) void k0_detect(
        const unsigned int* __restrict__ cm, int* flag_out, float* __restrict__ news_w) {
    __shared__ int word_gt1, byte_gt1;
    if (threadIdx.x == 0) { word_gt1 = 0; byte_gt1 = 0; }
    __syncthreads();
    int lw = 0, lb = 0;
    for (int i = threadIdx.x; i < 14400; i += blockDim.x) {
        unsigned int v = cm[i];
        if (v > 1u) lw = 1;
        if ((v & 0xFFu) > 1u || ((v >> 8) & 0xFFu) > 1u ||
            ((v >> 16) & 0xFFu) > 1u || ((v >> 24) & 0xFFu) > 1u) lb = 1;
    }
    if (lw) atomicOr(&word_gt1, 1);
    if (lb) atomicOr(&byte_gt1, 1);
    for (int i = threadIdx.x; i < BATCH * HIS; i += blockDim.x) news_w[i] = 0.f;
    __syncthreads();
    if (threadIdx.x == 0) {
        int f = 0;
        if (word_gt1) f = byte_gt1 ? 2 : 1;
        *flag_out = f;
    }
}

__global__ __launch_bounds__(256) void k2a_wt(
        const float* __restrict__ W, __hip_bfloat16* __restrict__ Wt) {
    __shared__ float t[32][33];
    int tx = threadIdx.x & 31, ty = threadIdx.x >> 5;
    int k0 = blockIdx.x * 32, n0 = blockIdx.y * 32;
    #pragma unroll
    for (int i = 0; i < 4; ++i)
        t[ty + i * 8][tx] = W[(size_t)(k0 + ty + i * 8) * EMBED + n0 + tx];
    __syncthreads();
    #pragma unroll
    for (int i = 0; i < 4; ++i)
        Wt[(size_t)(n0 + ty + i * 8) * EMBED + k0 + tx] =
            __float2bfloat16(t[tx][ty + i * 8]);
}

__global__ __launch_bounds__(192) void k1_pool(
        const int* __restrict__ enc, const void* amask,
        const float* __restrict__ wemb, __hip_bfloat16* __restrict__ pooled,
        const int* __restrict__ flagp) {
    int wave = threadIdx.x >> 6, lane = threadIdx.x & 63;
    int bh = blockIdx.x;
    int flag = *flagp;
    const int* e = enc + bh * SEQ;
    bool m = (lane < SEQ) ? read_mask(amask, bh * SEQ + lane, flag) : false;
    unsigned long long mb = __ballot(m);
    float cnt = (float)__popcll(mb);
    int fslot = wave * 64 + lane;
    float ax = 0.f, ay = 0.f, az = 0.f, aw = 0.f;
    #pragma unroll
    for (int s0 = 0; s0 < SEQ; s0 += 8) {
        float4 v[8];
        #pragma unroll
        for (int j = 0; j < 8; ++j)
            v[j] = ((const float4*)(wemb + (size_t)e[s0 + j] * EMBED))[fslot];
        #pragma unroll
        for (int j = 0; j < 8; ++j) {
            float mmv = ((mb >> (s0 + j)) & 1ull) ? 1.0f : 0.0f;
            ax += mmv * v[j].x; ay += mmv * v[j].y;
            az += mmv * v[j].z; aw += mmv * v[j].w;
        }
    }
    float d = 1.0f / fmaxf(cnt, 1.0f);
    ushort4 pk;
    pk.x = f2bf(ax * d); pk.y = f2bf(ay * d);
    pk.z = f2bf(az * d); pk.w = f2bf(aw * d);
    *(ushort4*)((unsigned short*)pooled + (size_t)bh * EMBED + fslot * 4) = pk;
}

// ---------------- K2: news_repr = tanh(pooled @ W + b) + fused news_w ----------------
#define GBM 128
#define GBK 64
#define LDP 72
__global__ __launch_bounds__(256) void k2_mfma(
        const __hip_bfloat16* __restrict__ A,   // pooled [3200][768]
        const __hip_bfloat16* __restrict__ Bt,  // Wt [768(n)][768(k)]
        const float* __restrict__ bias,
        const float* __restrict__ wna,          // w_news_attn [768]
        float* __restrict__ C,                  // news_repr [3200][768]
        float* __restrict__ news_w) {           // [3200], pre-zeroed
    __shared__ short As[GBM * LDP];
    __shared__ short Bs[GBM * LDP];
    int tid = threadIdx.x;
    int wave = tid >> 6, lane = tid & 63;
    int l15 = lane & 15, l4 = lane >> 4;
    int wr = wave >> 1, wc = wave & 1;
    int row0 = blockIdx.x * GBM;
    int col0 = blockIdx.y * GBM;
    v4f acc[4][4] = {};

    int r_st[4], c_st[4];
    #pragma unroll
    for (int it = 0; it < 4; ++it) {
        int chunk = tid + it * 256;
        r_st[it] = chunk >> 3; c_st[it] = chunk & 7;
    }

    v8s pa[4], pb[4];
    #pragma unroll
    for (int it = 0; it < 4; ++it) {
        pa[it] = *(const v8s*)(A  + (size_t)(row0 + r_st[it]) * EMBED + c_st[it] * 8);
        pb[it] = *(const v8s*)(Bt + (size_t)(col0 + r_st[it]) * EMBED + c_st[it] * 8);
    }

    for (int s = 0; s < EMBED / GBK; ++s) {
        #pragma unroll
        for (int it = 0; it < 4; ++it) {
            *(v8s*)&As[r_st[it] * LDP + c_st[it] * 8] = pa[it];
            *(v8s*)&Bs[r_st[it] * LDP + c_st[it] * 8] = pb[it];
        }
        __syncthreads();
        if (s < EMBED / GBK - 1) {
            int k0 = (s + 1) * GBK;
            #pragma unroll
            for (int it = 0; it < 4; ++it) {
                pa[it] = *(const v8s*)(A  + (size_t)(row0 + r_st[it]) * EMBED + k0 + c_st[it] * 8);
                pb[it] = *(const v8s*)(Bt + (size_t)(col0 + r_st[it]) * EMBED + k0 + c_st[it] * 8);
            }
        }
        #pragma unroll
        for (int kk = 0; kk < 2; ++kk) {
            v8s af[4], bf_[4];
            #pragma unroll
            for (int mi = 0; mi < 4; ++mi)
                af[mi] = *(const v8s*)&As[(wr * 64 + mi * 16 + l15) * LDP + kk * 32 + l4 * 8];
            #pragma unroll
            for (int ni = 0; ni < 4; ++ni)
                bf_[ni] = *(const v8s*)&Bs[(wc * 64 + ni * 16 + l15) * LDP + kk * 32 + l4 * 8];
            #pragma unroll
            for (int mi = 0; mi < 4; ++mi)
                #pragma unroll
                for (int ni = 0; ni < 4; ++ni)
                    acc[mi][ni] = __builtin_amdgcn_mfma_f32_16x16x32_bf16(
                        af[mi], bf_[ni], acc[mi][ni], 0, 0, 0);
        }
        __syncthreads();
    }
    // epilogue: tanh, store, and per-row partial dot with wna
    float bcol[4], wcol[4];
    #pragma unroll
    for (int ni = 0; ni < 4; ++ni) {
        int col = col0 + wc * 64 + ni * 16 + l15;
        bcol[ni] = bias[col]; wcol[ni] = wna[col];
    }
    #pragma unroll
    for (int mi = 0; mi < 4; ++mi) {
        #pragma unroll
        for (int r = 0; r < 4; ++r) {
            int row = row0 + wr * 64 + mi * 16 + l4 * 4 + r;
            float pr = 0.f;
            #pragma unroll
            for (int ni = 0; ni < 4; ++ni) {
                int col = col0 + wc * 64 + ni * 16 + l15;
                float tv = tanhf(acc[mi][ni][r] + bcol[ni]);
                C[(size_t)row * EMBED + col] = tv;
                pr += tv * wcol[ni];
            }
            pr += __shfl_xor(pr, 1); pr += __shfl_xor(pr, 2);
            pr += __shfl_xor(pr, 4); pr += __shfl_xor(pr, 8);
            if (l15 == 0) atomicAdd(&news_w[row], pr);
        }
    }
}

// ---------------- K4: fused cat softmax + einsum + logits + user ----------------
// one block per b, 768 threads (12 waves); thread owns one of 768 cols
__global__ __launch_bounds__(768) void k4_fused(
        const void* cmask, const float* __restrict__ nr,
        const float* __restrict__ news_w, const float* __restrict__ cat_emb,
        const float* __restrict__ w_cat, const float* __restrict__ click_emb,
        const float* __restrict__ click_w, const float* __restrict__ click_b,
        float* __restrict__ out_cat, float* __restrict__ user,
        const int* __restrict__ flagp) {
    int b = blockIdx.x, tid = threadIdx.x;
    int wave = tid >> 6, lane = tid & 63;
    int flag = *flagp;
    __shared__ float plds[HIS][20];      // attn weights transposed [h][c], pad 20
    __shared__ float redbuf[NUM_CAT][12];
    __shared__ float clicks[NUM_CAT];
    __shared__ int   cnts[NUM_CAT];
    __shared__ float logit[NUM_CAT];

    // ---- phase 1: per-cat masked softmax + click (c = wave, wave+12) ----
    for (int c = wave; c < NUM_CAT; c += 12) {
        bool m = false; float v = -INFINITY;
        if (lane < HIS) {
            m = read_mask(cmask, (b * NUM_CAT + c) * HIS + lane, flag);
            if (m) v = news_w[b * HIS + lane];
        }
        unsigned long long bal = __ballot(m);
        int cnt = __popcll(bal);
        float maxv = v;
        #pragma unroll
        for (int off = 32; off; off >>= 1) maxv = fmaxf(maxv, __shfl_xor(maxv, off));
        float e = (v == -INFINITY) ? 0.f : expf(v - maxv);
        float sum = e;
        #pragma unroll
        for (int off = 32; off; off >>= 1) sum += __shfl_xor(sum, off);
        if (lane < HIS)
            plds[lane][c] = (cnt == 0 || v == -INFINITY) ? 0.f : e / sum;
        float cs = 0.f;
        if (lane < HIS) {
            const float* ce = click_emb + (size_t)cnt * CLICK_DIM;
            cs = ce[lane] * click_w[lane] + ce[lane + HIS] * click_w[lane + HIS];
        }
        #pragma unroll
        for (int off = 32; off; off >>= 1) cs += __shfl_down(cs, off);
        if (lane == 0) { cnts[c] = cnt; clicks[c] = cs + click_b[0]; }
    }
    __syncthreads();

    // ---- phase 2: acc[c] = sum_h p[h][c] * nr[b][h][col] ----
    int col = tid;                        // 768 threads = EMBED
    const float* nrb = nr + (size_t)b * HIS * EMBED;
    float acc[NUM_CAT];
    #pragma unroll
    for (int c = 0; c < NUM_CAT; ++c) acc[c] = 0.f;
    for (int h = 0; h < HIS; ++h) {
        float v = nrb[h * EMBED + col];
        #pragma unroll
        for (int c = 0; c < NUM_CAT; ++c) acc[c] += plds[h][c] * v;
    }
    // epilogue: + cat_emb, store out_cat, partial catw dot
    float part[NUM_CAT];
    float wv = w_cat[col];
    float* ocb = out_cat + (size_t)b * NUM_CAT * EMBED;
    #pragma unroll
    for (int c = 0; c < NUM_CAT; ++c) {
        float o = acc[c] + cat_emb[c * EMBED + col];
        acc[c] = o;
        ocb[c * EMBED + col] = o;
        part[c] = o * wv;
    }
    #pragma unroll
    for (int c = 0; c < NUM_CAT; ++c) {
        float s = part[c];
        #pragma unroll
        for (int off = 32; off; off >>= 1) s += __shfl_down(s, off);
        if (lane == 0) redbuf[c][wave] = s;
    }
    __syncthreads();
    if (tid < NUM_CAT) {
        float s = 0.f;
        #pragma unroll
        for (int w = 0; w < 12; ++w) s += redbuf[tid][w];
        logit[tid] = (cnts[tid] == 0) ? -INFINITY : (s + clicks[tid]);
    }
    __syncthreads();

    // ---- phase 3: softmax over C + user_repr ----
    float maxv = -INFINITY;
    #pragma unroll
    for (int c = 0; c < NUM_CAT; ++c) maxv = fmaxf(maxv, logit[c]);
    float sum = 0.f;
    #pragma unroll
    for (int c = 0; c < NUM_CAT; ++c)
        sum += (logit[c] == -INFINITY) ? 0.f : expf(logit[c] - maxv);
    float u = 0.f;
    #pragma unroll
    for (int c = 0; c < NUM_CAT; ++c) {
        float w = (logit[c] == -INFINITY) ? 0.f : expf(logit[c] - maxv) / sum;
        u += w * acc[c];
    }
    user[(size_t)b * EMBED + col] = u;
}

extern "C" void kernel_launch(void* const* d_in, const int* in_sizes, int n_in,
                              void* d_out, int out_size, void* d_ws, size_t ws_size,
                              hipStream_t stream) {
    const int*   enc    = (const int*)d_in[0];
    const void*  amask  = d_in[1];
    const void*  cmask  = d_in[2];
    const float* wemb   = (const float*)d_in[3];
    const float* projw  = (const float*)d_in[4];
    const float* projb  = (const float*)d_in[5];
    const float* catemb = (const float*)d_in[6];
    const float* wna    = (const float*)d_in[7];
    const float* wca    = (const float*)d_in[8];
    const float* clemb  = (const float*)d_in[9];
    const float* clw    = (const float*)d_in[10];
    const float* clb    = (const float*)d_in[11];

    unsigned char* wsb = (unsigned char*)d_ws;
    __hip_bfloat16* pooled = (__hip_bfloat16*)(wsb + OFF_POOLED);
    __hip_bfloat16* Wt     = (__hip_bfloat16*)(wsb + OFF_WT);
    float* nr     = (float*)(wsb + OFF_NR);
    float* news_w = (float*)(wsb + OFF_NEWSW);
    int*   flag   = (int*)(wsb + OFF_FLAG);
    unsigned short* wtab = (unsigned short*)(wsb + OFF_WTAB);

    float* out_cat = (float*)d_out;
    float* user    = (float*)d_out + BATCH * NUM_CAT * EMBED;

    if (ws_size >= WS_NEED) {
        kprep<<<577 + CONV_BLOCKS, 256, 0, stream>>>(
            projw, Wt, (const unsigned int*)cmask, flag, wemb, wtab, news_w);
        k1b_pool<<<1600, 192, 0, stream>>>(enc, amask, wtab, pooled, flag);
    } else {
        k0_detect<<<1, 1024, 0, stream>>>((const unsigned int*)cmask, flag, news_w);
        dim3 gt(24, 24);
        k2a_wt<<<gt, 256, 0, stream>>>(projw, Wt);
        k1_pool<<<3200, 192, 0, stream>>>(enc, amask, wemb, pooled, flag);
    }
    dim3 g2(25, 6);
    k2_mfma<<<g2, 256, 0, stream>>>(pooled, Wt, projb, wna, nr, news_w);
    k4_fused<<<BATCH, 768, 0, stream>>>(cmask, nr, news_w, catemb, wca,
                                        clemb, clw, clb, out_cat, user, flag);
}

// Round 7
// 89.352 us; speedup vs baseline: 2.2448x; 1.0583x over previous
//
#include <hip/hip_runtime.h>
#include <hip/hip_bf16.h>
#include <math.h>

#define VOCAB 30522
#define EMBED 768
#define NUM_CAT 18
#define HIS 50
#define SEQ 32
#define BATCH 64
#define CLICK_DIM 100

typedef short v8s __attribute__((ext_vector_type(8)));
typedef float v4f __attribute__((ext_vector_type(4)));
typedef unsigned short v8u __attribute__((ext_vector_type(8)));

// ---------------- ws layout (byte offsets, 16B aligned) ----------------
#define OFF_POOLED 0            // bf16 [3200][768]           4,915,200 B
#define OFF_WT     4915200      // bf16 [768][768]            1,179,648 B
#define OFF_NR     6094848      // f32  [3200][768]           9,830,400 B
#define OFF_NEWSW  15925248     // f32  [3200]                   12,800 B
#define OFF_FLAG   16177664     // int
#define OFF_WTAB   16252928     // bf16 [30522][768]         46,881,792 B
#define WS_NEED    63134720ull

// flag: 0 = int32 mask, 1 = uint8 (np.bool_) mask, 2 = float32 mask
__device__ __forceinline__ bool read_mask(const void* p, int i, int flag) {
    if (flag == 0) return ((const int*)p)[i] != 0;
    if (flag == 1) return ((const unsigned char*)p)[i] != 0;
    return ((const float*)p)[i] != 0.0f;
}

__device__ __forceinline__ float bf2f(unsigned short u) {
    union { unsigned int i; float f; } cv;
    cv.i = ((unsigned int)u) << 16;
    return cv.f;
}
__device__ __forceinline__ unsigned short f2bf(float f) {
    __hip_bfloat16 h = __float2bfloat16(f);
    return *(unsigned short*)&h;
}

// ---------------- KPREP: Wt transpose + mask detect + news_w zero + wemb->bf16 ----------------
#define CONV_BLOCKS 2048
__global__ __launch_bounds__(256) void kprep(
        const float* __restrict__ W, __hip_bfloat16* __restrict__ Wt,
        const unsigned int* __restrict__ cm, int* __restrict__ flag_out,
        const float* __restrict__ wemb, unsigned short* __restrict__ wtab,
        float* __restrict__ news_w) {
    int blk = blockIdx.x;
    if (blk < 576) {
        __shared__ float t[32][33];
        int tx = threadIdx.x & 31, ty = threadIdx.x >> 5;
        int k0 = (blk % 24) * 32, n0 = (blk / 24) * 32;
        #pragma unroll
        for (int i = 0; i < 4; ++i)
            t[ty + i * 8][tx] = W[(size_t)(k0 + ty + i * 8) * EMBED + n0 + tx];
        __syncthreads();
        #pragma unroll
        for (int i = 0; i < 4; ++i)
            Wt[(size_t)(n0 + ty + i * 8) * EMBED + k0 + tx] =
                __float2bfloat16(t[tx][ty + i * 8]);
    } else if (blk == 576) {
        __shared__ int word_gt1, byte_gt1;
        if (threadIdx.x == 0) { word_gt1 = 0; byte_gt1 = 0; }
        __syncthreads();
        int lw = 0, lb = 0;
        for (int i = threadIdx.x; i < 14400; i += 256) {
            unsigned int v = cm[i];
            if (v > 1u) lw = 1;
            if ((v & 0xFFu) > 1u || ((v >> 8) & 0xFFu) > 1u ||
                ((v >> 16) & 0xFFu) > 1u || ((v >> 24) & 0xFFu) > 1u) lb = 1;
        }
        if (lw) atomicOr(&word_gt1, 1);
        if (lb) atomicOr(&byte_gt1, 1);
        for (int i = threadIdx.x; i < BATCH * HIS; i += 256) news_w[i] = 0.f;
        __syncthreads();
        if (threadIdx.x == 0) {
            int f = 0;
            if (word_gt1) f = byte_gt1 ? 2 : 1;
            *flag_out = f;
        }
    } else {
        const int N4 = (VOCAB * EMBED) / 4;
        int gtid = (blk - 577) * 256 + threadIdx.x;
        const float4* src = (const float4*)wemb;
        ushort4* dst = (ushort4*)wtab;
        for (int i = gtid; i < N4; i += CONV_BLOCKS * 256) {
            float4 v = src[i];
            ushort4 o;
            o.x = f2bf(v.x); o.y = f2bf(v.y); o.z = f2bf(v.z); o.w = f2bf(v.w);
            dst[i] = o;
        }
    }
}

// ---------------- K1B: gather (bf16 table) + masked mean pool ----------------
__global__ __launch_bounds__(192) void k1b_pool(
        const int* __restrict__ enc, const void* amask,
        const unsigned short* __restrict__ wtab, __hip_bfloat16* __restrict__ pooled,
        const int* __restrict__ flagp) {
    int tid = threadIdx.x, lane = tid & 63;
    int blk = blockIdx.x;                // [0,1600)
    int flag = *flagp;
    int bh0 = blk * 2, bh1 = blk * 2 + 1;
    bool mm = (lane < 32) ? read_mask(amask, bh0 * SEQ + lane, flag)
                          : read_mask(amask, bh1 * SEQ + (lane - 32), flag);
    unsigned long long bal = __ballot(mm);
    unsigned int mb0 = (unsigned int)(bal & 0xFFFFFFFFull);
    unsigned int mb1 = (unsigned int)(bal >> 32);
    int half = (tid >= 96) ? 1 : 0;
    int bh = half ? bh1 : bh0;
    unsigned int mb = half ? mb1 : mb0;
    float cnt = (float)__popc(mb);
    int slot = tid - half * 96;          // [0,96)
    const int* e = enc + bh * SEQ;
    float a[8] = {};
    #pragma unroll
    for (int s0 = 0; s0 < SEQ; s0 += 8) {
        v8u v[8];
        #pragma unroll
        for (int j = 0; j < 8; ++j)
            v[j] = ((const v8u*)(wtab + (size_t)e[s0 + j] * EMBED))[slot];
        #pragma unroll
        for (int j = 0; j < 8; ++j) {
            float m = ((mb >> (s0 + j)) & 1u) ? 1.0f : 0.0f;
            #pragma unroll
            for (int k = 0; k < 8; ++k) a[k] += m * bf2f(v[j][k]);
        }
    }
    float d = 1.0f / fmaxf(cnt, 1.0f);
    v8u o;
    #pragma unroll
    for (int k = 0; k < 8; ++k) o[k] = f2bf(a[k] * d);
    *(v8u*)(((unsigned short*)pooled) + (size_t)bh * EMBED + slot * 8) = o;
}

// ---------------- fallback path (ws too small) ----------------
__global__ __launch_bounds__(1024) void k0_detect(
        const unsigned int* __restrict__ cm, int* flag_out, float* __restrict__ news_w) {
    __shared__ int word_gt1, byte_gt1;
    if (threadIdx.x == 0) { word_gt1 = 0; byte_gt1 = 0; }
    __syncthreads();
    int lw = 0, lb = 0;
    for (int i = threadIdx.x; i < 14400; i += blockDim.x) {
        unsigned int v = cm[i];
        if (v > 1u) lw = 1;
        if ((v & 0xFFu) > 1u || ((v >> 8) & 0xFFu) > 1u ||
            ((v >> 16) & 0xFFu) > 1u || ((v >> 24) & 0xFFu) > 1u) lb = 1;
    }
    if (lw) atomicOr(&word_gt1, 1);
    if (lb) atomicOr(&byte_gt1, 1);
    for (int i = threadIdx.x; i < BATCH * HIS; i += blockDim.x) news_w[i] = 0.f;
    __syncthreads();
    if (threadIdx.x == 0) {
        int f = 0;
        if (word_gt1) f = byte_gt1 ? 2 : 1;
        *flag_out = f;
    }
}

__global__ __launch_bounds__(256) void k2a_wt(
        const float* __restrict__ W, __hip_bfloat16* __restrict__ Wt) {
    __shared__ float t[32][33];
    int tx = threadIdx.x & 31, ty = threadIdx.x >> 5;
    int k0 = blockIdx.x * 32, n0 = blockIdx.y * 32;
    #pragma unroll
    for (int i = 0; i < 4; ++i)
        t[ty + i * 8][tx] = W[(size_t)(k0 + ty + i * 8) * EMBED + n0 + tx];
    __syncthreads();
    #pragma unroll
    for (int i = 0; i < 4; ++i)
        Wt[(size_t)(n0 + ty + i * 8) * EMBED + k0 + tx] =
            __float2bfloat16(t[tx][ty + i * 8]);
}

__global__ __launch_bounds__(192) void k1_pool(
        const int* __restrict__ enc, const void* amask,
        const float* __restrict__ wemb, __hip_bfloat16* __restrict__ pooled,
        const int* __restrict__ flagp) {
    int wave = threadIdx.x >> 6, lane = threadIdx.x & 63;
    int bh = blockIdx.x;
    int flag = *flagp;
    const int* e = enc + bh * SEQ;
    bool m = (lane < SEQ) ? read_mask(amask, bh * SEQ + lane, flag) : false;
    unsigned long long mb = __ballot(m);
    float cnt = (float)__popcll(mb);
    int fslot = wave * 64 + lane;
    float ax = 0.f, ay = 0.f, az = 0.f, aw = 0.f;
    #pragma unroll
    for (int s0 = 0; s0 < SEQ; s0 += 8) {
        float4 v[8];
        #pragma unroll
        for (int j = 0; j < 8; ++j)
            v[j] = ((const float4*)(wemb + (size_t)e[s0 + j] * EMBED))[fslot];
        #pragma unroll
        for (int j = 0; j < 8; ++j) {
            float mmv = ((mb >> (s0 + j)) & 1ull) ? 1.0f : 0.0f;
            ax += mmv * v[j].x; ay += mmv * v[j].y;
            az += mmv * v[j].z; aw += mmv * v[j].w;
        }
    }
    float d = 1.0f / fmaxf(cnt, 1.0f);
    ushort4 pk;
    pk.x = f2bf(ax * d); pk.y = f2bf(ay * d);
    pk.z = f2bf(az * d); pk.w = f2bf(aw * d);
    *(ushort4*)((unsigned short*)pooled + (size_t)bh * EMBED + fslot * 4) = pk;
}

// ---------------- K2: news_repr = tanh(pooled @ W + b) + fused news_w ----------------
// 64x128 tile, BK=64, 4 waves (2x2, each 32x64 = 2x4 frags), grid 50x6 = 300 blocks
#define BM 64
#define BN 128
#define GBK 64
#define LDP 72
__global__ __launch_bounds__(256) void k2_mfma(
        const __hip_bfloat16* __restrict__ A,   // pooled [3200][768]
        const __hip_bfloat16* __restrict__ Bt,  // Wt [768(n)][768(k)]
        const float* __restrict__ bias,
        const float* __restrict__ wna,          // w_news_attn [768]
        float* __restrict__ C,                  // news_repr [3200][768]
        float* __restrict__ news_w) {           // [3200], pre-zeroed
    __shared__ short As[BM * LDP];
    __shared__ short Bs[BN * LDP];
    int tid = threadIdx.x;
    int wave = tid >> 6, lane = tid & 63;
    int l15 = lane & 15, l4 = lane >> 4;
    int wr = wave >> 1, wc = wave & 1;
    int row0 = blockIdx.x * BM;          // 50 row-blocks
    int col0 = blockIdx.y * BN;          // 6 col-blocks
    v4f acc[2][4] = {};

    // A staging: 64 rows x 8 chunks = 512; 2 per thread
    // B staging: 128 rows x 8 chunks = 1024; 4 per thread
    int ra[2], ca[2], rb[4], cb[4];
    #pragma unroll
    for (int it = 0; it < 2; ++it) {
        int chunk = tid + it * 256;
        ra[it] = chunk >> 3; ca[it] = chunk & 7;
    }
    #pragma unroll
    for (int it = 0; it < 4; ++it) {
        int chunk = tid + it * 256;
        rb[it] = chunk >> 3; cb[it] = chunk & 7;
    }

    v8s pa[2], pb[4];
    #pragma unroll
    for (int it = 0; it < 2; ++it)
        pa[it] = *(const v8s*)(A  + (size_t)(row0 + ra[it]) * EMBED + ca[it] * 8);
    #pragma unroll
    for (int it = 0; it < 4; ++it)
        pb[it] = *(const v8s*)(Bt + (size_t)(col0 + rb[it]) * EMBED + cb[it] * 8);

    for (int s = 0; s < EMBED / GBK; ++s) {
        #pragma unroll
        for (int it = 0; it < 2; ++it)
            *(v8s*)&As[ra[it] * LDP + ca[it] * 8] = pa[it];
        #pragma unroll
        for (int it = 0; it < 4; ++it)
            *(v8s*)&Bs[rb[it] * LDP + cb[it] * 8] = pb[it];
        __syncthreads();
        if (s < EMBED / GBK - 1) {
            int k0 = (s + 1) * GBK;
            #pragma unroll
            for (int it = 0; it < 2; ++it)
                pa[it] = *(const v8s*)(A  + (size_t)(row0 + ra[it]) * EMBED + k0 + ca[it] * 8);
            #pragma unroll
            for (int it = 0; it < 4; ++it)
                pb[it] = *(const v8s*)(Bt + (size_t)(col0 + rb[it]) * EMBED + k0 + cb[it] * 8);
        }
        #pragma unroll
        for (int kk = 0; kk < 2; ++kk) {
            v8s af[2], bf_[4];
            #pragma unroll
            for (int mi = 0; mi < 2; ++mi)
                af[mi] = *(const v8s*)&As[(wr * 32 + mi * 16 + l15) * LDP + kk * 32 + l4 * 8];
            #pragma unroll
            for (int ni = 0; ni < 4; ++ni)
                bf_[ni] = *(const v8s*)&Bs[(wc * 64 + ni * 16 + l15) * LDP + kk * 32 + l4 * 8];
            #pragma unroll
            for (int mi = 0; mi < 2; ++mi)
                #pragma unroll
                for (int ni = 0; ni < 4; ++ni)
                    acc[mi][ni] = __builtin_amdgcn_mfma_f32_16x16x32_bf16(
                        af[mi], bf_[ni], acc[mi][ni], 0, 0, 0);
        }
        __syncthreads();
    }
    // epilogue: tanh, store, per-row partial dot with wna (C/D map: col=lane&15, row=(lane>>4)*4+reg)
    float bcol[4], wcol[4];
    #pragma unroll
    for (int ni = 0; ni < 4; ++ni) {
        int col = col0 + wc * 64 + ni * 16 + l15;
        bcol[ni] = bias[col]; wcol[ni] = wna[col];
    }
    #pragma unroll
    for (int mi = 0; mi < 2; ++mi) {
        #pragma unroll
        for (int r = 0; r < 4; ++r) {
            int row = row0 + wr * 32 + mi * 16 + l4 * 4 + r;
            float pr = 0.f;
            #pragma unroll
            for (int ni = 0; ni < 4; ++ni) {
                int col = col0 + wc * 64 + ni * 16 + l15;
                float tv = tanhf(acc[mi][ni][r] + bcol[ni]);
                C[(size_t)row * EMBED + col] = tv;
                pr += tv * wcol[ni];
            }
            pr += __shfl_xor(pr, 1); pr += __shfl_xor(pr, 2);
            pr += __shfl_xor(pr, 4); pr += __shfl_xor(pr, 8);
            if (l15 == 0) atomicAdd(&news_w[row], pr);
        }
    }
}

// ---------------- K4: fused cat softmax + einsum + logits + user ----------------
__global__ __launch_bounds__(768) void k4_fused(
        const void* cmask, const float* __restrict__ nr,
        const float* __restrict__ news_w, const float* __restrict__ cat_emb,
        const float* __restrict__ w_cat, const float* __restrict__ click_emb,
        const float* __restrict__ click_w, const float* __restrict__ click_b,
        float* __restrict__ out_cat, float* __restrict__ user,
        const int* __restrict__ flagp) {
    int b = blockIdx.x, tid = threadIdx.x;
    int wave = tid >> 6, lane = tid & 63;
    int flag = *flagp;
    __shared__ float plds[HIS][20];
    __shared__ float redbuf[NUM_CAT][12];
    __shared__ float clicks[NUM_CAT];
    __shared__ int   cnts[NUM_CAT];
    __shared__ float logit[NUM_CAT];

    for (int c = wave; c < NUM_CAT; c += 12) {
        bool m = false; float v = -INFINITY;
        if (lane < HIS) {
            m = read_mask(cmask, (b * NUM_CAT + c) * HIS + lane, flag);
            if (m) v = news_w[b * HIS + lane];
        }
        unsigned long long bal = __ballot(m);
        int cnt = __popcll(bal);
        float maxv = v;
        #pragma unroll
        for (int off = 32; off; off >>= 1) maxv = fmaxf(maxv, __shfl_xor(maxv, off));
        float e = (v == -INFINITY) ? 0.f : expf(v - maxv);
        float sum = e;
        #pragma unroll
        for (int off = 32; off; off >>= 1) sum += __shfl_xor(sum, off);
        if (lane < HIS)
            plds[lane][c] = (cnt == 0 || v == -INFINITY) ? 0.f : e / sum;
        float cs = 0.f;
        if (lane < HIS) {
            const float* ce = click_emb + (size_t)cnt * CLICK_DIM;
            cs = ce[lane] * click_w[lane] + ce[lane + HIS] * click_w[lane + HIS];
        }
        #pragma unroll
        for (int off = 32; off; off >>= 1) cs += __shfl_down(cs, off);
        if (lane == 0) { cnts[c] = cnt; clicks[c] = cs + click_b[0]; }
    }
    __syncthreads();

    int col = tid;
    const float* nrb = nr + (size_t)b * HIS * EMBED;
    float acc[NUM_CAT];
    #pragma unroll
    for (int c = 0; c < NUM_CAT; ++c) acc[c] = 0.f;
    #pragma unroll 5
    for (int h = 0; h < HIS; ++h) {
        float v = nrb[h * EMBED + col];
        #pragma unroll
        for (int c = 0; c < NUM_CAT; ++c) acc[c] += plds[h][c] * v;
    }
    float part[NUM_CAT];
    float wv = w_cat[col];
    float* ocb = out_cat + (size_t)b * NUM_CAT * EMBED;
    #pragma unroll
    for (int c = 0; c < NUM_CAT; ++c) {
        float o = acc[c] + cat_emb[c * EMBED + col];
        acc[c] = o;
        ocb[c * EMBED + col] = o;
        part[c] = o * wv;
    }
    #pragma unroll
    for (int c = 0; c < NUM_CAT; ++c) {
        float s = part[c];
        #pragma unroll
        for (int off = 32; off; off >>= 1) s += __shfl_down(s, off);
        if (lane == 0) redbuf[c][wave] = s;
    }
    __syncthreads();
    if (tid < NUM_CAT) {
        float s = 0.f;
        #pragma unroll
        for (int w = 0; w < 12; ++w) s += redbuf[tid][w];
        logit[tid] = (cnts[tid] == 0) ? -INFINITY : (s + clicks[tid]);
    }
    __syncthreads();

    float maxv = -INFINITY;
    #pragma unroll
    for (int c = 0; c < NUM_CAT; ++c) maxv = fmaxf(maxv, logit[c]);
    float sum = 0.f;
    #pragma unroll
    for (int c = 0; c < NUM_CAT; ++c)
        sum += (logit[c] == -INFINITY) ? 0.f : expf(logit[c] - maxv);
    float u = 0.f;
    #pragma unroll
    for (int c = 0; c < NUM_CAT; ++c) {
        float w = (logit[c] == -INFINITY) ? 0.f : expf(logit[c] - maxv) / sum;
        u += w * acc[c];
    }
    user[(size_t)b * EMBED + col] = u;
}

extern "C" void kernel_launch(void* const* d_in, const int* in_sizes, int n_in,
                              void* d_out, int out_size, void* d_ws, size_t ws_size,
                              hipStream_t stream) {
    const int*   enc    = (const int*)d_in[0];
    const void*  amask  = d_in[1];
    const void*  cmask  = d_in[2];
    const float* wemb   = (const float*)d_in[3];
    const float* projw  = (const float*)d_in[4];
    const float* projb  = (const float*)d_in[5];
    const float* catemb = (const float*)d_in[6];
    const float* wna    = (const float*)d_in[7];
    const float* wca    = (const float*)d_in[8];
    const float* clemb  = (const float*)d_in[9];
    const float* clw    = (const float*)d_in[10];
    const float* clb    = (const float*)d_in[11];

    unsigned char* wsb = (unsigned char*)d_ws;
    __hip_bfloat16* pooled = (__hip_bfloat16*)(wsb + OFF_POOLED);
    __hip_bfloat16* Wt     = (__hip_bfloat16*)(wsb + OFF_WT);
    float* nr     = (float*)(wsb + OFF_NR);
    float* news_w = (float*)(wsb + OFF_NEWSW);
    int*   flag   = (int*)(wsb + OFF_FLAG);
    unsigned short* wtab = (unsigned short*)(wsb + OFF_WTAB);

    float* out_cat = (float*)d_out;
    float* user    = (float*)d_out + BATCH * NUM_CAT * EMBED;

    if (ws_size >= WS_NEED) {
        kprep<<<577 + CONV_BLOCKS, 256, 0, stream>>>(
            projw, Wt, (const unsigned int*)cmask, flag, wemb, wtab, news_w);
        k1b_pool<<<1600, 192, 0, stream>>>(enc, amask, wtab, pooled, flag);
    } else {
        k0_detect<<<1, 1024, 0, stream>>>((const unsigned int*)cmask, flag, news_w);
        dim3 gt(24, 24);
        k2a_wt<<<gt, 256, 0, stream>>>(projw, Wt);
        k1_pool<<<3200, 192, 0, stream>>>(enc, amask, wemb, pooled, flag);
    }
    dim3 g2(50, 6);
    k2_mfma<<<g2, 256, 0, stream>>>(pooled, Wt, projb, wna, nr, news_w);
    k4_fused<<<BATCH, 768, 0, stream>>>(cmask, nr, news_w, catemb, wca,
                                        clemb, clw, clb, out_cat, user, flag);
}

// Round 8
// 88.532 us; speedup vs baseline: 2.2656x; 1.0093x over previous
//
#include <hip/hip_runtime.h>
#include <hip/hip_bf16.h>
#include <math.h>

#define VOCAB 30522
#define EMBED 768
#define NUM_CAT 18
#define HIS 50
#define SEQ 32
#define BATCH 64
#define CLICK_DIM 100

typedef short v8s __attribute__((ext_vector_type(8)));
typedef float v4f __attribute__((ext_vector_type(4)));
typedef unsigned short v8u __attribute__((ext_vector_type(8)));

// ---------------- ws layout (byte offsets, 16B aligned) ----------------
#define OFF_POOLED 0            // bf16 [3200][768]           4,915,200 B
#define OFF_WT     4915200      // bf16 [768][768]            1,179,648 B
#define OFF_NR     6094848      // f32  [3200][768]           9,830,400 B
#define OFF_NEWSW  15925248     // f32  [3200]                   12,800 B
#define OFF_FLAG   16177664     // int
#define OFF_WTAB   16252928     // bf16 [30522][768]         46,881,792 B
#define WS_NEED    63134720ull

// flag: 0 = int32 mask, 1 = uint8 (np.bool_) mask, 2 = float32 mask
__device__ __forceinline__ bool read_mask(const void* p, int i, int flag) {
    if (flag == 0) return ((const int*)p)[i] != 0;
    if (flag == 1) return ((const unsigned char*)p)[i] != 0;
    return ((const float*)p)[i] != 0.0f;
}

__device__ __forceinline__ float bf2f(unsigned short u) {
    union { unsigned int i; float f; } cv;
    cv.i = ((unsigned int)u) << 16;
    return cv.f;
}
__device__ __forceinline__ unsigned short f2bf(float f) {
    __hip_bfloat16 h = __float2bfloat16(f);
    return *(unsigned short*)&h;
}

// ---------------- KPREP: Wt transpose + mask detect + news_w zero + wemb->bf16 ----------------
#define CONV_BLOCKS 2048
__global__ __launch_bounds__(256) void kprep(
        const float* __restrict__ W, __hip_bfloat16* __restrict__ Wt,
        const unsigned int* __restrict__ cm, int* __restrict__ flag_out,
        const float* __restrict__ wemb, unsigned short* __restrict__ wtab,
        float* __restrict__ news_w) {
    int blk = blockIdx.x;
    if (blk < 576) {
        __shared__ float t[32][33];
        int tx = threadIdx.x & 31, ty = threadIdx.x >> 5;
        int k0 = (blk % 24) * 32, n0 = (blk / 24) * 32;
        #pragma unroll
        for (int i = 0; i < 4; ++i)
            t[ty + i * 8][tx] = W[(size_t)(k0 + ty + i * 8) * EMBED + n0 + tx];
        __syncthreads();
        #pragma unroll
        for (int i = 0; i < 4; ++i)
            Wt[(size_t)(n0 + ty + i * 8) * EMBED + k0 + tx] =
                __float2bfloat16(t[tx][ty + i * 8]);
    } else if (blk == 576) {
        __shared__ int word_gt1, byte_gt1;
        if (threadIdx.x == 0) { word_gt1 = 0; byte_gt1 = 0; }
        __syncthreads();
        int lw = 0, lb = 0;
        for (int i = threadIdx.x; i < 14400; i += 256) {
            unsigned int v = cm[i];
            if (v > 1u) lw = 1;
            if ((v & 0xFFu) > 1u || ((v >> 8) & 0xFFu) > 1u ||
                ((v >> 16) & 0xFFu) > 1u || ((v >> 24) & 0xFFu) > 1u) lb = 1;
        }
        if (lw) atomicOr(&word_gt1, 1);
        if (lb) atomicOr(&byte_gt1, 1);
        for (int i = threadIdx.x; i < BATCH * HIS; i += 256) news_w[i] = 0.f;
        __syncthreads();
        if (threadIdx.x == 0) {
            int f = 0;
            if (word_gt1) f = byte_gt1 ? 2 : 1;
            *flag_out = f;
        }
    } else {
        const int N4 = (VOCAB * EMBED) / 4;
        int gtid = (blk - 577) * 256 + threadIdx.x;
        const float4* src = (const float4*)wemb;
        ushort4* dst = (ushort4*)wtab;
        for (int i = gtid; i < N4; i += CONV_BLOCKS * 256) {
            float4 v = src[i];
            ushort4 o;
            o.x = f2bf(v.x); o.y = f2bf(v.y); o.z = f2bf(v.z); o.w = f2bf(v.w);
            dst[i] = o;
        }
    }
}

// ---------------- K1B: gather (bf16 table) + masked mean pool ----------------
__global__ __launch_bounds__(192) void k1b_pool(
        const int* __restrict__ enc, const void* amask,
        const unsigned short* __restrict__ wtab, __hip_bfloat16* __restrict__ pooled,
        const int* __restrict__ flagp) {
    int tid = threadIdx.x, lane = tid & 63;
    int blk = blockIdx.x;                // [0,1600)
    int flag = *flagp;
    int bh0 = blk * 2, bh1 = blk * 2 + 1;
    bool mm = (lane < 32) ? read_mask(amask, bh0 * SEQ + lane, flag)
                          : read_mask(amask, bh1 * SEQ + (lane - 32), flag);
    unsigned long long bal = __ballot(mm);
    unsigned int mb0 = (unsigned int)(bal & 0xFFFFFFFFull);
    unsigned int mb1 = (unsigned int)(bal >> 32);
    int half = (tid >= 96) ? 1 : 0;
    int bh = half ? bh1 : bh0;
    unsigned int mb = half ? mb1 : mb0;
    float cnt = (float)__popc(mb);
    int slot = tid - half * 96;          // [0,96)
    const int* e = enc + bh * SEQ;
    float a[8] = {};
    #pragma unroll
    for (int s0 = 0; s0 < SEQ; s0 += 8) {
        v8u v[8];
        #pragma unroll
        for (int j = 0; j < 8; ++j)
            v[j] = ((const v8u*)(wtab + (size_t)e[s0 + j] * EMBED))[slot];
        #pragma unroll
        for (int j = 0; j < 8; ++j) {
            float m = ((mb >> (s0 + j)) & 1u) ? 1.0f : 0.0f;
            #pragma unroll
            for (int k = 0; k < 8; ++k) a[k] += m * bf2f(v[j][k]);
        }
    }
    float d = 1.0f / fmaxf(cnt, 1.0f);
    v8u o;
    #pragma unroll
    for (int k = 0; k < 8; ++k) o[k] = f2bf(a[k] * d);
    *(v8u*)(((unsigned short*)pooled) + (size_t)bh * EMBED + slot * 8) = o;
}

// ---------------- fallback path (ws too small) ----------------
__global__ __launch_bounds__(1024) void k0_detect(
        const unsigned int* __restrict__ cm, int* flag_out, float* __restrict__ news_w) {
    __shared__ int word_gt1, byte_gt1;
    if (threadIdx.x == 0) { word_gt1 = 0; byte_gt1 = 0; }
    __syncthreads();
    int lw = 0, lb = 0;
    for (int i = threadIdx.x; i < 14400; i += blockDim.x) {
        unsigned int v = cm[i];
        if (v > 1u) lw = 1;
        if ((v & 0xFFu) > 1u || ((v >> 8) & 0xFFu) > 1u ||
            ((v >> 16) & 0xFFu) > 1u || ((v >> 24) & 0xFFu) > 1u) lb = 1;
    }
    if (lw) atomicOr(&word_gt1, 1);
    if (lb) atomicOr(&byte_gt1, 1);
    for (int i = threadIdx.x; i < BATCH * HIS; i += blockDim.x) news_w[i] = 0.f;
    __syncthreads();
    if (threadIdx.x == 0) {
        int f = 0;
        if (word_gt1) f = byte_gt1 ? 2 : 1;
        *flag_out = f;
    }
}

__global__ __launch_bounds__(256) void k2a_wt(
        const float* __restrict__ W, __hip_bfloat16* __restrict__ Wt) {
    __shared__ float t[32][33];
    int tx = threadIdx.x & 31, ty = threadIdx.x >> 5;
    int k0 = blockIdx.x * 32, n0 = blockIdx.y * 32;
    #pragma unroll
    for (int i = 0; i < 4; ++i)
        t[ty + i * 8][tx] = W[(size_t)(k0 + ty + i * 8) * EMBED + n0 + tx];
    __syncthreads();
    #pragma unroll
    for (int i = 0; i < 4; ++i)
        Wt[(size_t)(n0 + ty + i * 8) * EMBED + k0 + tx] =
            __float2bfloat16(t[tx][ty + i * 8]);
}

__global__ __launch_bounds__(192) void k1_pool(
        const int* __restrict__ enc, const void* amask,
        const float* __restrict__ wemb, __hip_bfloat16* __restrict__ pooled,
        const int* __restrict__ flagp) {
    int wave = threadIdx.x >> 6, lane = threadIdx.x & 63;
    int bh = blockIdx.x;
    int flag = *flagp;
    const int* e = enc + bh * SEQ;
    bool m = (lane < SEQ) ? read_mask(amask, bh * SEQ + lane, flag) : false;
    unsigned long long mb = __ballot(m);
    float cnt = (float)__popcll(mb);
    int fslot = wave * 64 + lane;
    float ax = 0.f, ay = 0.f, az = 0.f, aw = 0.f;
    #pragma unroll
    for (int s0 = 0; s0 < SEQ; s0 += 8) {
        float4 v[8];
        #pragma unroll
        for (int j = 0; j < 8; ++j)
            v[j] = ((const float4*)(wemb + (size_t)e[s0 + j] * EMBED))[fslot];
        #pragma unroll
        for (int j = 0; j < 8; ++j) {
            float mmv = ((mb >> (s0 + j)) & 1ull) ? 1.0f : 0.0f;
            ax += mmv * v[j].x; ay += mmv * v[j].y;
            az += mmv * v[j].z; aw += mmv * v[j].w;
        }
    }
    float d = 1.0f / fmaxf(cnt, 1.0f);
    ushort4 pk;
    pk.x = f2bf(ax * d); pk.y = f2bf(ay * d);
    pk.z = f2bf(az * d); pk.w = f2bf(aw * d);
    *(ushort4*)((unsigned short*)pooled + (size_t)bh * EMBED + fslot * 4) = pk;
}

// ---------------- K2: news_repr = tanh(pooled @ W + b) + fused news_w ----------------
// 64x128 tile, BK=64, 4 waves (2x2, each 32x64 = 2x4 frags), grid 50x6 = 300 blocks
#define BM 64
#define BN 128
#define GBK 64
#define LDP 72
__global__ __launch_bounds__(256) void k2_mfma(
        const __hip_bfloat16* __restrict__ A,   // pooled [3200][768]
        const __hip_bfloat16* __restrict__ Bt,  // Wt [768(n)][768(k)]
        const float* __restrict__ bias,
        const float* __restrict__ wna,          // w_news_attn [768]
        float* __restrict__ C,                  // news_repr [3200][768]
        float* __restrict__ news_w) {           // [3200], pre-zeroed
    __shared__ short As[BM * LDP];
    __shared__ short Bs[BN * LDP];
    int tid = threadIdx.x;
    int wave = tid >> 6, lane = tid & 63;
    int l15 = lane & 15, l4 = lane >> 4;
    int wr = wave >> 1, wc = wave & 1;
    int row0 = blockIdx.x * BM;          // 50 row-blocks
    int col0 = blockIdx.y * BN;          // 6 col-blocks
    v4f acc[2][4] = {};

    // A staging: 64 rows x 8 chunks = 512; 2 per thread
    // B staging: 128 rows x 8 chunks = 1024; 4 per thread
    int ra[2], ca[2], rb[4], cb[4];
    #pragma unroll
    for (int it = 0; it < 2; ++it) {
        int chunk = tid + it * 256;
        ra[it] = chunk >> 3; ca[it] = chunk & 7;
    }
    #pragma unroll
    for (int it = 0; it < 4; ++it) {
        int chunk = tid + it * 256;
        rb[it] = chunk >> 3; cb[it] = chunk & 7;
    }

    v8s pa[2], pb[4];
    #pragma unroll
    for (int it = 0; it < 2; ++it)
        pa[it] = *(const v8s*)(A  + (size_t)(row0 + ra[it]) * EMBED + ca[it] * 8);
    #pragma unroll
    for (int it = 0; it < 4; ++it)
        pb[it] = *(const v8s*)(Bt + (size_t)(col0 + rb[it]) * EMBED + cb[it] * 8);

    for (int s = 0; s < EMBED / GBK; ++s) {
        #pragma unroll
        for (int it = 0; it < 2; ++it)
            *(v8s*)&As[ra[it] * LDP + ca[it] * 8] = pa[it];
        #pragma unroll
        for (int it = 0; it < 4; ++it)
            *(v8s*)&Bs[rb[it] * LDP + cb[it] * 8] = pb[it];
        __syncthreads();
        if (s < EMBED / GBK - 1) {
            int k0 = (s + 1) * GBK;
            #pragma unroll
            for (int it = 0; it < 2; ++it)
                pa[it] = *(const v8s*)(A  + (size_t)(row0 + ra[it]) * EMBED + k0 + ca[it] * 8);
            #pragma unroll
            for (int it = 0; it < 4; ++it)
                pb[it] = *(const v8s*)(Bt + (size_t)(col0 + rb[it]) * EMBED + k0 + cb[it] * 8);
        }
        #pragma unroll
        for (int kk = 0; kk < 2; ++kk) {
            v8s af[2], bf_[4];
            #pragma unroll
            for (int mi = 0; mi < 2; ++mi)
                af[mi] = *(const v8s*)&As[(wr * 32 + mi * 16 + l15) * LDP + kk * 32 + l4 * 8];
            #pragma unroll
            for (int ni = 0; ni < 4; ++ni)
                bf_[ni] = *(const v8s*)&Bs[(wc * 64 + ni * 16 + l15) * LDP + kk * 32 + l4 * 8];
            #pragma unroll
            for (int mi = 0; mi < 2; ++mi)
                #pragma unroll
                for (int ni = 0; ni < 4; ++ni)
                    acc[mi][ni] = __builtin_amdgcn_mfma_f32_16x16x32_bf16(
                        af[mi], bf_[ni], acc[mi][ni], 0, 0, 0);
        }
        __syncthreads();
    }
    // epilogue: tanh, store, per-row partial dot with wna (C/D map: col=lane&15, row=(lane>>4)*4+reg)
    float bcol[4], wcol[4];
    #pragma unroll
    for (int ni = 0; ni < 4; ++ni) {
        int col = col0 + wc * 64 + ni * 16 + l15;
        bcol[ni] = bias[col]; wcol[ni] = wna[col];
    }
    #pragma unroll
    for (int mi = 0; mi < 2; ++mi) {
        #pragma unroll
        for (int r = 0; r < 4; ++r) {
            int row = row0 + wr * 32 + mi * 16 + l4 * 4 + r;
            float pr = 0.f;
            #pragma unroll
            for (int ni = 0; ni < 4; ++ni) {
                int col = col0 + wc * 64 + ni * 16 + l15;
                float tv = tanhf(acc[mi][ni][r] + bcol[ni]);
                C[(size_t)row * EMBED + col] = tv;
                pr += tv * wcol[ni];
            }
            pr += __shfl_xor(pr, 1); pr += __shfl_xor(pr, 2);
            pr += __shfl_xor(pr, 4); pr += __shfl_xor(pr, 8);
            if (l15 == 0) atomicAdd(&news_w[row], pr);
        }
    }
}

// ---------------- K4: fused cat softmax + einsum + logits + user ----------------
__global__ __launch_bounds__(768) void k4_fused(
        const void* cmask, const float* __restrict__ nr,
        const float* __restrict__ news_w, const float* __restrict__ cat_emb,
        const float* __restrict__ w_cat, const float* __restrict__ click_emb,
        const float* __restrict__ click_w, const float* __restrict__ click_b,
        float* __restrict__ out_cat, float* __restrict__ user,
        const int* __restrict__ flagp) {
    int b = blockIdx.x, tid = threadIdx.x;
    int wave = tid >> 6, lane = tid & 63;
    int flag = *flagp;
    __shared__ float plds[HIS][20];
    __shared__ float redbuf[NUM_CAT][12];
    __shared__ float clicks[NUM_CAT];
    __shared__ int   cnts[NUM_CAT];
    __shared__ float logit[NUM_CAT];

    for (int c = wave; c < NUM_CAT; c += 12) {
        bool m = false; float v = -INFINITY;
        if (lane < HIS) {
            m = read_mask(cmask, (b * NUM_CAT + c) * HIS + lane, flag);
            if (m) v = news_w[b * HIS + lane];
        }
        unsigned long long bal = __ballot(m);
        int cnt = __popcll(bal);
        float maxv = v;
        #pragma unroll
        for (int off = 32; off; off >>= 1) maxv = fmaxf(maxv, __shfl_xor(maxv, off));
        float e = (v == -INFINITY) ? 0.f : expf(v - maxv);
        float sum = e;
        #pragma unroll
        for (int off = 32; off; off >>= 1) sum += __shfl_xor(sum, off);
        if (lane < HIS)
            plds[lane][c] = (cnt == 0 || v == -INFINITY) ? 0.f : e / sum;
        float cs = 0.f;
        if (lane < HIS) {
            const float* ce = click_emb + (size_t)cnt * CLICK_DIM;
            cs = ce[lane] * click_w[lane] + ce[lane + HIS] * click_w[lane + HIS];
        }
        #pragma unroll
        for (int off = 32; off; off >>= 1) cs += __shfl_down(cs, off);
        if (lane == 0) { cnts[c] = cnt; clicks[c] = cs + click_b[0]; }
    }
    __syncthreads();

    int col = tid;
    const float* nrb = nr + (size_t)b * HIS * EMBED;
    float acc[NUM_CAT];
    #pragma unroll
    for (int c = 0; c < NUM_CAT; ++c) acc[c] = 0.f;
    #pragma unroll 5
    for (int h = 0; h < HIS; ++h) {
        float v = nrb[h * EMBED + col];
        #pragma unroll
        for (int c = 0; c < NUM_CAT; ++c) acc[c] += plds[h][c] * v;
    }
    float part[NUM_CAT];
    float wv = w_cat[col];
    float* ocb = out_cat + (size_t)b * NUM_CAT * EMBED;
    #pragma unroll
    for (int c = 0; c < NUM_CAT; ++c) {
        float o = acc[c] + cat_emb[c * EMBED + col];
        acc[c] = o;
        ocb[c * EMBED + col] = o;
        part[c] = o * wv;
    }
    #pragma unroll
    for (int c = 0; c < NUM_CAT; ++c) {
        float s = part[c];
        #pragma unroll
        for (int off = 32; off; off >>= 1) s += __shfl_down(s, off);
        if (lane == 0) redbuf[c][wave] = s;
    }
    __syncthreads();
    if (tid < NUM_CAT) {
        float s = 0.f;
        #pragma unroll
        for (int w = 0; w < 12; ++w) s += redbuf[tid][w];
        logit[tid] = (cnts[tid] == 0) ? -INFINITY : (s + clicks[tid]);
    }
    __syncthreads();

    float maxv = -INFINITY;
    #pragma unroll
    for (int c = 0; c < NUM_CAT; ++c) maxv = fmaxf(maxv, logit[c]);
    float sum = 0.f;
    #pragma unroll
    for (int c = 0; c < NUM_CAT; ++c)
        sum += (logit[c] == -INFINITY) ? 0.f : expf(logit[c] - maxv);
    float u = 0.f;
    #pragma unroll
    for (int c = 0; c < NUM_CAT; ++c) {
        float w = (logit[c] == -INFINITY) ? 0.f : expf(logit[c] - maxv) / sum;
        u += w * acc[c];
    }
    user[(size_t)b * EMBED + col] = u;
}

extern "C" void kernel_launch(void* const* d_in, const int* in_sizes, int n_in,
                              void* d_out, int out_size, void* d_ws, size_t ws_size,
                              hipStream_t stream) {
    const int*   enc    = (const int*)d_in[0];
    const void*  amask  = d_in[1];
    const void*  cmask  = d_in[2];
    const float* wemb   = (const float*)d_in[3];
    const float* projw  = (const float*)d_in[4];
    const float* projb  = (const float*)d_in[5];
    const float* catemb = (const float*)d_in[6];
    const float* wna    = (const float*)d_in[7];
    const float* wca    = (const float*)d_in[8];
    const float* clemb  = (const float*)d_in[9];
    const float* clw    = (const float*)d_in[10];
    const float* clb    = (const float*)d_in[11];

    unsigned char* wsb = (unsigned char*)d_ws;
    __hip_bfloat16* pooled = (__hip_bfloat16*)(wsb + OFF_POOLED);
    __hip_bfloat16* Wt     = (__hip_bfloat16*)(wsb + OFF_WT);
    float* nr     = (float*)(wsb + OFF_NR);
    float* news_w = (float*)(wsb + OFF_NEWSW);
    int*   flag   = (int*)(wsb + OFF_FLAG);
    unsigned short* wtab = (unsigned short*)(wsb + OFF_WTAB);

    float* out_cat = (float*)d_out;
    float* user    = (float*)d_out + BATCH * NUM_CAT * EMBED;

    if (ws_size >= WS_NEED) {
        kprep<<<577 + CONV_BLOCKS, 256, 0, stream>>>(
            projw, Wt, (const unsigned int*)cmask, flag, wemb, wtab, news_w);
        k1b_pool<<<1600, 192, 0, stream>>>(enc, amask, wtab, pooled, flag);
    } else {
        k0_detect<<<1, 1024, 0, stream>>>((const unsigned int*)cmask, flag, news_w);
        dim3 gt(24, 24);
        k2a_wt<<<gt, 256, 0, stream>>>(projw, Wt);
        k1_pool<<<3200, 192, 0, stream>>>(enc, amask, wemb, pooled, flag);
    }
    dim3 g2(50, 6);
    k2_mfma<<<g2, 256, 0, stream>>>(pooled, Wt, projb, wna, nr, news_w);
    k4_fused<<<BATCH, 768, 0, stream>>>(cmask, nr, news_w, catemb, wca,
                                        clemb, clw, clb, out_cat, user, flag);
}

// Round 9
// 87.275 us; speedup vs baseline: 2.2982x; 1.0144x over previous
//
#include <hip/hip_runtime.h>
#include <hip/hip_bf16.h>
#include <math.h>

#define VOCAB 30522
#define EMBED 768
#define NUM_CAT 18
#define HIS 50
#define SEQ 32
#define BATCH 64
#define CLICK_DIM 100

typedef short v8s __attribute__((ext_vector_type(8)));
typedef float v4f __attribute__((ext_vector_type(4)));
typedef unsigned short v8u __attribute__((ext_vector_type(8)));

// ---------------- ws layout (byte offsets, 16B aligned) ----------------
#define OFF_POOLED 0            // bf16 [3200][768]           4,915,200 B
#define OFF_WT     4915200      // bf16 [768][768]            1,179,648 B
#define OFF_NR     6094848      // bf16 [3200][768]           4,915,200 B
#define OFF_NEWSW  15925248     // f32  [3200]                   12,800 B
#define OFF_FLAG   16177664     // int
#define OFF_WTAB   16252928     // bf16 [30522][768]         46,881,792 B
#define WS_NEED    63134720ull

// flag: 0 = int32 mask, 1 = uint8 (np.bool_) mask, 2 = float32 mask
__device__ __forceinline__ bool read_mask(const void* p, int i, int flag) {
    if (flag == 0) return ((const int*)p)[i] != 0;
    if (flag == 1) return ((const unsigned char*)p)[i] != 0;
    return ((const float*)p)[i] != 0.0f;
}

__device__ __forceinline__ float bf2f(unsigned short u) {
    union { unsigned int i; float f; } cv;
    cv.i = ((unsigned int)u) << 16;
    return cv.f;
}
__device__ __forceinline__ unsigned short f2bf(float f) {
    __hip_bfloat16 h = __float2bfloat16(f);
    return *(unsigned short*)&h;
}

// ---------------- KPREP: Wt transpose + mask detect + news_w zero + wemb->bf16 ----------------
#define CONV_BLOCKS 2048
__global__ __launch_bounds__(256) void kprep(
        const float* __restrict__ W, __hip_bfloat16* __restrict__ Wt,
        const unsigned int* __restrict__ cm, int* __restrict__ flag_out,
        const float* __restrict__ wemb, unsigned short* __restrict__ wtab,
        float* __restrict__ news_w) {
    int blk = blockIdx.x;
    if (blk < 576) {
        __shared__ float t[32][33];
        int tx = threadIdx.x & 31, ty = threadIdx.x >> 5;
        int k0 = (blk % 24) * 32, n0 = (blk / 24) * 32;
        #pragma unroll
        for (int i = 0; i < 4; ++i)
            t[ty + i * 8][tx] = W[(size_t)(k0 + ty + i * 8) * EMBED + n0 + tx];
        __syncthreads();
        #pragma unroll
        for (int i = 0; i < 4; ++i)
            Wt[(size_t)(n0 + ty + i * 8) * EMBED + k0 + tx] =
                __float2bfloat16(t[tx][ty + i * 8]);
    } else if (blk == 576) {
        __shared__ int word_gt1, byte_gt1;
        if (threadIdx.x == 0) { word_gt1 = 0; byte_gt1 = 0; }
        __syncthreads();
        int lw = 0, lb = 0;
        for (int i = threadIdx.x; i < 14400; i += 256) {
            unsigned int v = cm[i];
            if (v > 1u) lw = 1;
            if ((v & 0xFFu) > 1u || ((v >> 8) & 0xFFu) > 1u ||
                ((v >> 16) & 0xFFu) > 1u || ((v >> 24) & 0xFFu) > 1u) lb = 1;
        }
        if (lw) atomicOr(&word_gt1, 1);
        if (lb) atomicOr(&byte_gt1, 1);
        for (int i = threadIdx.x; i < BATCH * HIS; i += 256) news_w[i] = 0.f;
        __syncthreads();
        if (threadIdx.x == 0) {
            int f = 0;
            if (word_gt1) f = byte_gt1 ? 2 : 1;
            *flag_out = f;
        }
    } else {
        // wtab = bf16(wemb): 2x float4 read -> 1x ushort8 store
        const int N8 = (VOCAB * EMBED) / 8;           // 2,930,112
        int gtid = (blk - 577) * 256 + threadIdx.x;
        const float4* src = (const float4*)wemb;
        v8u* dst = (v8u*)wtab;
        for (int i = gtid; i < N8; i += CONV_BLOCKS * 256) {
            float4 a = src[2 * i], b = src[2 * i + 1];
            v8u o;
            o[0] = f2bf(a.x); o[1] = f2bf(a.y); o[2] = f2bf(a.z); o[3] = f2bf(a.w);
            o[4] = f2bf(b.x); o[5] = f2bf(b.y); o[6] = f2bf(b.z); o[7] = f2bf(b.w);
            dst[i] = o;
        }
    }
}

// ---------------- K1B: gather (bf16 table) + masked mean pool, 16-deep pipeline ----------------
__global__ __launch_bounds__(192) void k1b_pool(
        const int* __restrict__ enc, const void* amask,
        const unsigned short* __restrict__ wtab, __hip_bfloat16* __restrict__ pooled,
        const int* __restrict__ flagp) {
    int tid = threadIdx.x, lane = tid & 63;
    int blk = blockIdx.x;                // [0,1600)
    int flag = *flagp;
    int bh0 = blk * 2, bh1 = blk * 2 + 1;
    bool mm = (lane < 32) ? read_mask(amask, bh0 * SEQ + lane, flag)
                          : read_mask(amask, bh1 * SEQ + (lane - 32), flag);
    unsigned long long bal = __ballot(mm);
    unsigned int mb0 = (unsigned int)(bal & 0xFFFFFFFFull);
    unsigned int mb1 = (unsigned int)(bal >> 32);
    int half = (tid >= 96) ? 1 : 0;
    int bh = half ? bh1 : bh0;
    unsigned int mb = half ? mb1 : mb0;
    float cnt = (float)__popc(mb);
    int slot = tid - half * 96;          // [0,96)
    const int* e = enc + bh * SEQ;
    float a[8] = {};
    v8u v[8], w[8];
    #pragma unroll
    for (int j = 0; j < 8; ++j)
        v[j] = ((const v8u*)(wtab + (size_t)e[j] * EMBED))[slot];
    #pragma unroll
    for (int s0 = 0; s0 < SEQ; s0 += 8) {
        if (s0 + 8 < SEQ) {
            #pragma unroll
            for (int j = 0; j < 8; ++j)
                w[j] = ((const v8u*)(wtab + (size_t)e[s0 + 8 + j] * EMBED))[slot];
        }
        #pragma unroll
        for (int j = 0; j < 8; ++j) {
            float m = ((mb >> (s0 + j)) & 1u) ? 1.0f : 0.0f;
            #pragma unroll
            for (int k = 0; k < 8; ++k) a[k] += m * bf2f(v[j][k]);
        }
        #pragma unroll
        for (int j = 0; j < 8; ++j) v[j] = w[j];
    }
    float d = 1.0f / fmaxf(cnt, 1.0f);
    v8u o;
    #pragma unroll
    for (int k = 0; k < 8; ++k) o[k] = f2bf(a[k] * d);
    *(v8u*)(((unsigned short*)pooled) + (size_t)bh * EMBED + slot * 8) = o;
}

// ---------------- fallback path (ws too small) ----------------
__global__ __launch_bounds__(1024) void k0_detect(
        const unsigned int* __restrict__ cm, int* flag_out, float* __restrict__ news_w) {
    __shared__ int word_gt1, byte_gt1;
    if (threadIdx.x == 0) { word_gt1 = 0; byte_gt1 = 0; }
    __syncthreads();
    int lw = 0, lb = 0;
    for (int i = threadIdx.x; i < 14400; i += blockDim.x) {
        unsigned int v = cm[i];
        if (v > 1u) lw = 1;
        if ((v & 0xFFu) > 1u || ((v >> 8) & 0xFFu) > 1u ||
            ((v >> 16) & 0xFFu) > 1u || ((v >> 24) & 0xFFu) > 1u) lb = 1;
    }
    if (lw) atomicOr(&word_gt1, 1);
    if (lb) atomicOr(&byte_gt1, 1);
    for (int i = threadIdx.x; i < BATCH * HIS; i += blockDim.x) news_w[i] = 0.f;
    __syncthreads();
    if (threadIdx.x == 0) {
        int f = 0;
        if (word_gt1) f = byte_gt1 ? 2 : 1;
        *flag_out = f;
    }
}

__global__ __launch_bounds__(256) void k2a_wt(
        const float* __restrict__ W, __hip_bfloat16* __restrict__ Wt) {
    __shared__ float t[32][33];
    int tx = threadIdx.x & 31, ty = threadIdx.x >> 5;
    int k0 = blockIdx.x * 32, n0 = blockIdx.y * 32;
    #pragma unroll
    for (int i = 0; i < 4; ++i)
        t[ty + i * 8][tx] = W[(size_t)(k0 + ty + i * 8) * EMBED + n0 + tx];
    __syncthreads();
    #pragma unroll
    for (int i = 0; i < 4; ++i)
        Wt[(size_t)(n0 + ty + i * 8) * EMBED + k0 + tx] =
            __float2bfloat16(t[tx][ty + i * 8]);
}

__global__ __launch_bounds__(192) void k1_pool(
        const int* __restrict__ enc, const void* amask,
        const float* __restrict__ wemb, __hip_bfloat16* __restrict__ pooled,
        const int* __restrict__ flagp) {
    int wave = threadIdx.x >> 6, lane = threadIdx.x & 63;
    int bh = blockIdx.x;
    int flag = *flagp;
    const int* e = enc + bh * SEQ;
    bool m = (lane < SEQ) ? read_mask(amask, bh * SEQ + lane, flag) : false;
    unsigned long long mb = __ballot(m);
    float cnt = (float)__popcll(mb);
    int fslot = wave * 64 + lane;
    float ax = 0.f, ay = 0.f, az = 0.f, aw = 0.f;
    #pragma unroll
    for (int s0 = 0; s0 < SEQ; s0 += 8) {
        float4 v[8];
        #pragma unroll
        for (int j = 0; j < 8; ++j)
            v[j] = ((const float4*)(wemb + (size_t)e[s0 + j] * EMBED))[fslot];
        #pragma unroll
        for (int j = 0; j < 8; ++j) {
            float mmv = ((mb >> (s0 + j)) & 1ull) ? 1.0f : 0.0f;
            ax += mmv * v[j].x; ay += mmv * v[j].y;
            az += mmv * v[j].z; aw += mmv * v[j].w;
        }
    }
    float d = 1.0f / fmaxf(cnt, 1.0f);
    ushort4 pk;
    pk.x = f2bf(ax * d); pk.y = f2bf(ay * d);
    pk.z = f2bf(az * d); pk.w = f2bf(aw * d);
    *(ushort4*)((unsigned short*)pooled + (size_t)bh * EMBED + fslot * 4) = pk;
}

// ---------------- K2: news_repr = tanh(pooled @ W + b) -> bf16, + fused news_w ----------------
// 64x64 tile, BK=64, 4 waves (2x2, each 32x32 = 2x2 frags), grid 50x12 = 600 blocks
#define BM 64
#define BN 64
#define GBK 64
#define LDP 72
__global__ __launch_bounds__(256) void k2_mfma(
        const __hip_bfloat16* __restrict__ A,   // pooled [3200][768]
        const __hip_bfloat16* __restrict__ Bt,  // Wt [768(n)][768(k)]
        const float* __restrict__ bias,
        const float* __restrict__ wna,          // w_news_attn [768]
        unsigned short* __restrict__ C,         // news_repr bf16 [3200][768]
        float* __restrict__ news_w) {           // [3200], pre-zeroed
    __shared__ short As[BM * LDP];
    __shared__ short Bs[BN * LDP];
    int tid = threadIdx.x;
    int wave = tid >> 6, lane = tid & 63;
    int l15 = lane & 15, l4 = lane >> 4;
    int wr = wave >> 1, wc = wave & 1;
    int row0 = blockIdx.x * BM;          // 50 row-blocks
    int col0 = blockIdx.y * BN;          // 12 col-blocks
    v4f acc[2][2] = {};

    // staging: 64 rows x 8 chunks = 512 each; 2 per thread
    int ra[2], ca[2];
    #pragma unroll
    for (int it = 0; it < 2; ++it) {
        int chunk = tid + it * 256;
        ra[it] = chunk >> 3; ca[it] = chunk & 7;
    }

    v8s pa[2], pb[2];
    #pragma unroll
    for (int it = 0; it < 2; ++it) {
        pa[it] = *(const v8s*)(A  + (size_t)(row0 + ra[it]) * EMBED + ca[it] * 8);
        pb[it] = *(const v8s*)(Bt + (size_t)(col0 + ra[it]) * EMBED + ca[it] * 8);
    }

    for (int s = 0; s < EMBED / GBK; ++s) {
        #pragma unroll
        for (int it = 0; it < 2; ++it) {
            *(v8s*)&As[ra[it] * LDP + ca[it] * 8] = pa[it];
            *(v8s*)&Bs[ra[it] * LDP + ca[it] * 8] = pb[it];
        }
        __syncthreads();
        if (s < EMBED / GBK - 1) {
            int k0 = (s + 1) * GBK;
            #pragma unroll
            for (int it = 0; it < 2; ++it) {
                pa[it] = *(const v8s*)(A  + (size_t)(row0 + ra[it]) * EMBED + k0 + ca[it] * 8);
                pb[it] = *(const v8s*)(Bt + (size_t)(col0 + ra[it]) * EMBED + k0 + ca[it] * 8);
            }
        }
        #pragma unroll
        for (int kk = 0; kk < 2; ++kk) {
            v8s af[2], bf_[2];
            #pragma unroll
            for (int mi = 0; mi < 2; ++mi)
                af[mi] = *(const v8s*)&As[(wr * 32 + mi * 16 + l15) * LDP + kk * 32 + l4 * 8];
            #pragma unroll
            for (int ni = 0; ni < 2; ++ni)
                bf_[ni] = *(const v8s*)&Bs[(wc * 32 + ni * 16 + l15) * LDP + kk * 32 + l4 * 8];
            #pragma unroll
            for (int mi = 0; mi < 2; ++mi)
                #pragma unroll
                for (int ni = 0; ni < 2; ++ni)
                    acc[mi][ni] = __builtin_amdgcn_mfma_f32_16x16x32_bf16(
                        af[mi], bf_[ni], acc[mi][ni], 0, 0, 0);
        }
        __syncthreads();
    }
    // epilogue (C/D map: col=lane&15, row=(lane>>4)*4+reg)
    float bcol[2], wcol[2];
    #pragma unroll
    for (int ni = 0; ni < 2; ++ni) {
        int col = col0 + wc * 32 + ni * 16 + l15;
        bcol[ni] = bias[col]; wcol[ni] = wna[col];
    }
    #pragma unroll
    for (int mi = 0; mi < 2; ++mi) {
        #pragma unroll
        for (int r = 0; r < 4; ++r) {
            int row = row0 + wr * 32 + mi * 16 + l4 * 4 + r;
            float pr = 0.f;
            #pragma unroll
            for (int ni = 0; ni < 2; ++ni) {
                int col = col0 + wc * 32 + ni * 16 + l15;
                float tv = tanhf(acc[mi][ni][r] + bcol[ni]);
                C[(size_t)row * EMBED + col] = f2bf(tv);
                pr += tv * wcol[ni];
            }
            pr += __shfl_xor(pr, 1); pr += __shfl_xor(pr, 2);
            pr += __shfl_xor(pr, 4); pr += __shfl_xor(pr, 8);
            if (l15 == 0) atomicAdd(&news_w[row], pr);
        }
    }
}

// ---------------- K4: fused cat softmax + einsum + logits + user ----------------
__global__ __launch_bounds__(768) void k4_fused(
        const void* cmask, const unsigned short* __restrict__ nr,
        const float* __restrict__ news_w, const float* __restrict__ cat_emb,
        const float* __restrict__ w_cat, const float* __restrict__ click_emb,
        const float* __restrict__ click_w, const float* __restrict__ click_b,
        float* __restrict__ out_cat, float* __restrict__ user,
        const int* __restrict__ flagp) {
    int b = blockIdx.x, tid = threadIdx.x;
    int wave = tid >> 6, lane = tid & 63;
    int flag = *flagp;
    __shared__ float plds[HIS][20];
    __shared__ float redbuf[NUM_CAT][12];
    __shared__ float clicks[NUM_CAT];
    __shared__ int   cnts[NUM_CAT];
    __shared__ float logit[NUM_CAT];

    for (int c = wave; c < NUM_CAT; c += 12) {
        bool m = false; float v = -INFINITY;
        if (lane < HIS) {
            m = read_mask(cmask, (b * NUM_CAT + c) * HIS + lane, flag);
            if (m) v = news_w[b * HIS + lane];
        }
        unsigned long long bal = __ballot(m);
        int cnt = __popcll(bal);
        float maxv = v;
        #pragma unroll
        for (int off = 32; off; off >>= 1) maxv = fmaxf(maxv, __shfl_xor(maxv, off));
        float e = (v == -INFINITY) ? 0.f : expf(v - maxv);
        float sum = e;
        #pragma unroll
        for (int off = 32; off; off >>= 1) sum += __shfl_xor(sum, off);
        if (lane < HIS)
            plds[lane][c] = (cnt == 0 || v == -INFINITY) ? 0.f : e / sum;
        float cs = 0.f;
        if (lane < HIS) {
            const float* ce = click_emb + (size_t)cnt * CLICK_DIM;
            cs = ce[lane] * click_w[lane] + ce[lane + HIS] * click_w[lane + HIS];
        }
        #pragma unroll
        for (int off = 32; off; off >>= 1) cs += __shfl_down(cs, off);
        if (lane == 0) { cnts[c] = cnt; clicks[c] = cs + click_b[0]; }
    }
    __syncthreads();

    int col = tid;
    const unsigned short* nrb = nr + (size_t)b * HIS * EMBED;
    float acc[NUM_CAT];
    #pragma unroll
    for (int c = 0; c < NUM_CAT; ++c) acc[c] = 0.f;
    #pragma unroll 5
    for (int h = 0; h < HIS; ++h) {
        float v = bf2f(nrb[h * EMBED + col]);
        #pragma unroll
        for (int c = 0; c < NUM_CAT; ++c) acc[c] += plds[h][c] * v;
    }
    float part[NUM_CAT];
    float wv = w_cat[col];
    float* ocb = out_cat + (size_t)b * NUM_CAT * EMBED;
    #pragma unroll
    for (int c = 0; c < NUM_CAT; ++c) {
        float o = acc[c] + cat_emb[c * EMBED + col];
        acc[c] = o;
        ocb[c * EMBED + col] = o;
        part[c] = o * wv;
    }
    #pragma unroll
    for (int c = 0; c < NUM_CAT; ++c) {
        float s = part[c];
        #pragma unroll
        for (int off = 32; off; off >>= 1) s += __shfl_down(s, off);
        if (lane == 0) redbuf[c][wave] = s;
    }
    __syncthreads();
    if (tid < NUM_CAT) {
        float s = 0.f;
        #pragma unroll
        for (int w = 0; w < 12; ++w) s += redbuf[tid][w];
        logit[tid] = (cnts[tid] == 0) ? -INFINITY : (s + clicks[tid]);
    }
    __syncthreads();

    float maxv = -INFINITY;
    #pragma unroll
    for (int c = 0; c < NUM_CAT; ++c) maxv = fmaxf(maxv, logit[c]);
    float sum = 0.f;
    #pragma unroll
    for (int c = 0; c < NUM_CAT; ++c)
        sum += (logit[c] == -INFINITY) ? 0.f : expf(logit[c] - maxv);
    float u = 0.f;
    #pragma unroll
    for (int c = 0; c < NUM_CAT; ++c) {
        float w = (logit[c] == -INFINITY) ? 0.f : expf(logit[c] - maxv) / sum;
        u += w * acc[c];
    }
    user[(size_t)b * EMBED + col] = u;
}

extern "C" void kernel_launch(void* const* d_in, const int* in_sizes, int n_in,
                              void* d_out, int out_size, void* d_ws, size_t ws_size,
                              hipStream_t stream) {
    const int*   enc    = (const int*)d_in[0];
    const void*  amask  = d_in[1];
    const void*  cmask  = d_in[2];
    const float* wemb   = (const float*)d_in[3];
    const float* projw  = (const float*)d_in[4];
    const float* projb  = (const float*)d_in[5];
    const float* catemb = (const float*)d_in[6];
    const float* wna    = (const float*)d_in[7];
    const float* wca    = (const float*)d_in[8];
    const float* clemb  = (const float*)d_in[9];
    const float* clw    = (const float*)d_in[10];
    const float* clb    = (const float*)d_in[11];

    unsigned char* wsb = (unsigned char*)d_ws;
    __hip_bfloat16* pooled = (__hip_bfloat16*)(wsb + OFF_POOLED);
    __hip_bfloat16* Wt     = (__hip_bfloat16*)(wsb + OFF_WT);
    unsigned short* nr     = (unsigned short*)(wsb + OFF_NR);
    float* news_w = (float*)(wsb + OFF_NEWSW);
    int*   flag   = (int*)(wsb + OFF_FLAG);
    unsigned short* wtab = (unsigned short*)(wsb + OFF_WTAB);

    float* out_cat = (float*)d_out;
    float* user    = (float*)d_out + BATCH * NUM_CAT * EMBED;

    if (ws_size >= WS_NEED) {
        kprep<<<577 + CONV_BLOCKS, 256, 0, stream>>>(
            projw, Wt, (const unsigned int*)cmask, flag, wemb, wtab, news_w);
        k1b_pool<<<1600, 192, 0, stream>>>(enc, amask, wtab, pooled, flag);
    } else {
        k0_detect<<<1, 1024, 0, stream>>>((const unsigned int*)cmask, flag, news_w);
        dim3 gt(24, 24);
        k2a_wt<<<gt, 256, 0, stream>>>(projw, Wt);
        k1_pool<<<3200, 192, 0, stream>>>(enc, amask, wemb, pooled, flag);
    }
    dim3 g2(50, 12);
    k2_mfma<<<g2, 256, 0, stream>>>(pooled, Wt, projb, wna, nr, news_w);
    k4_fused<<<BATCH, 768, 0, stream>>>(cmask, nr, news_w, catemb, wca,
                                        clemb, clw, clb, out_cat, user, flag);
}

// Round 10
// 76.715 us; speedup vs baseline: 2.6146x; 1.1377x over previous
//
#include <hip/hip_runtime.h>
#include <hip/hip_bf16.h>
#include <math.h>

#define VOCAB 30522
#define EMBED 768
#define NUM_CAT 18
#define HIS 50
#define SEQ 32
#define BATCH 64
#define CLICK_DIM 100

typedef short v8s __attribute__((ext_vector_type(8)));
typedef float v4f __attribute__((ext_vector_type(4)));
typedef unsigned short v8u __attribute__((ext_vector_type(8)));
typedef unsigned char v8c __attribute__((ext_vector_type(8)));

// ---------------- ws layout (byte offsets, 16B aligned) ----------------
#define OFF_POOLED 0            // bf16 [3200][768]           4,915,200 B
#define OFF_WT     4915200      // bf16 [768][768]            1,179,648 B
#define OFF_NR     6094848      // bf16 [3200][768]           4,915,200 B
#define OFF_NEWSW  15925248     // f32  [3200]                   12,800 B
#define OFF_FLAG   16177664     // int
#define OFF_QTAB   16252928     // int8 [30522][768]         23,440,896 B
#define OFF_DSCALE 39693824     // f32  [30522]                 122,088 B
#define WS_NEED    39815912ull

// flag: 0 = int32 mask, 1 = uint8 (np.bool_) mask, 2 = float32 mask
__device__ __forceinline__ bool read_mask(const void* p, int i, int flag) {
    if (flag == 0) return ((const int*)p)[i] != 0;
    if (flag == 1) return ((const unsigned char*)p)[i] != 0;
    return ((const float*)p)[i] != 0.0f;
}

__device__ __forceinline__ float bf2f(unsigned short u) {
    union { unsigned int i; float f; } cv;
    cv.i = ((unsigned int)u) << 16;
    return cv.f;
}
__device__ __forceinline__ unsigned short f2bf(float f) {
    __hip_bfloat16 h = __float2bfloat16(f);
    return *(unsigned short*)&h;
}

// ---------------- KPREP: Wt transpose + mask detect + news_w zero + wemb->int8 ----------------
// blocks [0,576): Wt transpose; 576: detect+zero; [577, 577+30522): per-row int8 quant
__global__ __launch_bounds__(256) void kprep(
        const float* __restrict__ W, __hip_bfloat16* __restrict__ Wt,
        const unsigned int* __restrict__ cm, int* __restrict__ flag_out,
        const float* __restrict__ wemb, signed char* __restrict__ qtab,
        float* __restrict__ dscales, float* __restrict__ news_w) {
    int blk = blockIdx.x;
    if (blk < 576) {
        __shared__ float t[32][33];
        int tx = threadIdx.x & 31, ty = threadIdx.x >> 5;
        int k0 = (blk % 24) * 32, n0 = (blk / 24) * 32;
        #pragma unroll
        for (int i = 0; i < 4; ++i)
            t[ty + i * 8][tx] = W[(size_t)(k0 + ty + i * 8) * EMBED + n0 + tx];
        __syncthreads();
        #pragma unroll
        for (int i = 0; i < 4; ++i)
            Wt[(size_t)(n0 + ty + i * 8) * EMBED + k0 + tx] =
                __float2bfloat16(t[tx][ty + i * 8]);
    } else if (blk == 576) {
        __shared__ int word_gt1, byte_gt1;
        if (threadIdx.x == 0) { word_gt1 = 0; byte_gt1 = 0; }
        __syncthreads();
        int lw = 0, lb = 0;
        for (int i = threadIdx.x; i < 14400; i += 256) {
            unsigned int v = cm[i];
            if (v > 1u) lw = 1;
            if ((v & 0xFFu) > 1u || ((v >> 8) & 0xFFu) > 1u ||
                ((v >> 16) & 0xFFu) > 1u || ((v >> 24) & 0xFFu) > 1u) lb = 1;
        }
        if (lw) atomicOr(&word_gt1, 1);
        if (lb) atomicOr(&byte_gt1, 1);
        for (int i = threadIdx.x; i < BATCH * HIS; i += 256) news_w[i] = 0.f;
        __syncthreads();
        if (threadIdx.x == 0) {
            int f = 0;
            if (word_gt1) f = byte_gt1 ? 2 : 1;
            *flag_out = f;
        }
    } else {
        // per-row symmetric int8 quant: threads 0..191 own 4 consecutive cols
        __shared__ float red[4];
        int row = blk - 577;              // [0, 30522)
        int tid = threadIdx.x, lane = tid & 63, wv = tid >> 6;
        float4 v = make_float4(0.f, 0.f, 0.f, 0.f);
        if (tid < 192)
            v = *(const float4*)(wemb + (size_t)row * EMBED + tid * 4);
        float mx = fmaxf(fmaxf(fabsf(v.x), fabsf(v.y)),
                         fmaxf(fabsf(v.z), fabsf(v.w)));
        #pragma unroll
        for (int off = 32; off; off >>= 1) mx = fmaxf(mx, __shfl_xor(mx, off));
        if (lane == 0) red[wv] = mx;
        __syncthreads();
        float rowmax = fmaxf(fmaxf(red[0], red[1]), red[2]);
        if (tid < 192) {
            float inv = (rowmax > 0.f) ? 127.0f / rowmax : 0.f;
            int q0 = __float2int_rn(v.x * inv);
            int q1 = __float2int_rn(v.y * inv);
            int q2 = __float2int_rn(v.z * inv);
            int q3 = __float2int_rn(v.w * inv);
            q0 = max(-127, min(127, q0)); q1 = max(-127, min(127, q1));
            q2 = max(-127, min(127, q2)); q3 = max(-127, min(127, q3));
            char4 c; c.x = (signed char)q0; c.y = (signed char)q1;
            c.z = (signed char)q2; c.w = (signed char)q3;
            *(char4*)(qtab + (size_t)row * EMBED + tid * 4) = c;
        }
        if (tid == 0) dscales[row] = rowmax * (1.0f / 127.0f);
    }
}

// ---------------- K1C: gather (int8 table) + masked mean pool, 16-deep pipeline ----------------
// 2 rows per block, 192 threads; thread owns uchar8 (8B) slot: 96 slots/row
__global__ __launch_bounds__(192) void k1c_pool(
        const int* __restrict__ enc, const void* amask,
        const unsigned char* __restrict__ qtab, const float* __restrict__ dscales,
        __hip_bfloat16* __restrict__ pooled, const int* __restrict__ flagp) {
    int tid = threadIdx.x, lane = tid & 63;
    int blk = blockIdx.x;                // [0,1600)
    int flag = *flagp;
    int bh0 = blk * 2, bh1 = blk * 2 + 1;
    bool mm = (lane < 32) ? read_mask(amask, bh0 * SEQ + lane, flag)
                          : read_mask(amask, bh1 * SEQ + (lane - 32), flag);
    unsigned long long bal = __ballot(mm);
    unsigned int mb0 = (unsigned int)(bal & 0xFFFFFFFFull);
    unsigned int mb1 = (unsigned int)(bal >> 32);
    int half = (tid >= 96) ? 1 : 0;
    int bh = half ? bh1 : bh0;
    unsigned int mb = half ? mb1 : mb0;
    float cnt = (float)__popc(mb);
    int slot = tid - half * 96;          // [0,96)
    const int* e = enc + bh * SEQ;
    float a[8] = {};
    v8c v[8], w[8];
    float ds[8], dw[8];
    #pragma unroll
    for (int j = 0; j < 8; ++j) {
        int tok = e[j];
        v[j] = ((const v8c*)(qtab + (size_t)tok * EMBED))[slot];
        ds[j] = dscales[tok];
    }
    #pragma unroll
    for (int s0 = 0; s0 < SEQ; s0 += 8) {
        if (s0 + 8 < SEQ) {
            #pragma unroll
            for (int j = 0; j < 8; ++j) {
                int tok = e[s0 + 8 + j];
                w[j] = ((const v8c*)(qtab + (size_t)tok * EMBED))[slot];
                dw[j] = dscales[tok];
            }
        }
        #pragma unroll
        for (int j = 0; j < 8; ++j) {
            float msc = ((mb >> (s0 + j)) & 1u) ? ds[j] : 0.f;
            #pragma unroll
            for (int k = 0; k < 8; ++k) {
                int q = (int)(signed char)v[j][k];
                a[k] = fmaf((float)q, msc, a[k]);
            }
        }
        #pragma unroll
        for (int j = 0; j < 8; ++j) { v[j] = w[j]; ds[j] = dw[j]; }
    }
    float d = 1.0f / fmaxf(cnt, 1.0f);
    v8u o;
    #pragma unroll
    for (int k = 0; k < 8; ++k) o[k] = f2bf(a[k] * d);
    *(v8u*)(((unsigned short*)pooled) + (size_t)bh * EMBED + slot * 8) = o;
}

// ---------------- fallback path (ws too small) ----------------
__global__ __launch_bounds__(1024) void k0_detect(
        const unsigned int* __restrict__ cm, int* flag_out, float* __restrict__ news_w) {
    __shared__ int word_gt1, byte_gt1;
    if (threadIdx.x == 0) { word_gt1 = 0; byte_gt1 = 0; }
    __syncthreads();
    int lw = 0, lb = 0;
    for (int i = threadIdx.x; i < 14400; i += blockDim.x) {
        unsigned int v = cm[i];
        if (v > 1u) lw = 1;
        if ((v & 0xFFu) > 1u || ((v >> 8) & 0xFFu) > 1u ||
            ((v >> 16) & 0xFFu) > 1u || ((v >> 24) & 0xFFu) > 1u) lb = 1;
    }
    if (lw) atomicOr(&word_gt1, 1);
    if (lb) atomicOr(&byte_gt1, 1);
    for (int i = threadIdx.x; i < BATCH * HIS; i += blockDim.x) news_w[i] = 0.f;
    __syncthreads();
    if (threadIdx.x == 0) {
        int f = 0;
        if (word_gt1) f = byte_gt1 ? 2 : 1;
        *flag_out = f;
    }
}

__global__ __launch_bounds__(256) void k2a_wt(
        const float* __restrict__ W, __hip_bfloat16* __restrict__ Wt) {
    __shared__ float t[32][33];
    int tx = threadIdx.x & 31, ty = threadIdx.x >> 5;
    int k0 = blockIdx.x * 32, n0 = blockIdx.y * 32;
    #pragma unroll
    for (int i = 0; i < 4; ++i)
        t[ty + i * 8][tx] = W[(size_t)(k0 + ty + i * 8) * EMBED + n0 + tx];
    __syncthreads();
    #pragma unroll
    for (int i = 0; i < 4; ++i)
        Wt[(size_t)(n0 + ty + i * 8) * EMBED + k0 + tx] =
            __float2bfloat16(t[tx][ty + i * 8]);
}

__global__ __launch_bounds__(192) void k1_pool(
        const int* __restrict__ enc, const void* amask,
        const float* __restrict__ wemb, __hip_bfloat16* __restrict__ pooled,
        const int* __restrict__ flagp) {
    int wave = threadIdx.x >> 6, lane = threadIdx.x & 63;
    int bh = blockIdx.x;
    int flag = *flagp;
    const int* e = enc + bh * SEQ;
    bool m = (lane < SEQ) ? read_mask(amask, bh * SEQ + lane, flag) : false;
    unsigned long long mb = __ballot(m);
    float cnt = (float)__popcll(mb);
    int fslot = wave * 64 + lane;
    float ax = 0.f, ay = 0.f, az = 0.f, aw = 0.f;
    #pragma unroll
    for (int s0 = 0; s0 < SEQ; s0 += 8) {
        float4 v[8];
        #pragma unroll
        for (int j = 0; j < 8; ++j)
            v[j] = ((const float4*)(wemb + (size_t)e[s0 + j] * EMBED))[fslot];
        #pragma unroll
        for (int j = 0; j < 8; ++j) {
            float mmv = ((mb >> (s0 + j)) & 1ull) ? 1.0f : 0.0f;
            ax += mmv * v[j].x; ay += mmv * v[j].y;
            az += mmv * v[j].z; aw += mmv * v[j].w;
        }
    }
    float d = 1.0f / fmaxf(cnt, 1.0f);
    ushort4 pk;
    pk.x = f2bf(ax * d); pk.y = f2bf(ay * d);
    pk.z = f2bf(az * d); pk.w = f2bf(aw * d);
    *(ushort4*)((unsigned short*)pooled + (size_t)bh * EMBED + fslot * 4) = pk;
}

// ---------------- K2: news_repr = tanh(pooled @ W + b) -> bf16, + fused news_w ----------------
// 64x64 tile, BK=64, 4 waves (2x2, each 32x32 = 2x2 frags), grid 50x12 = 600 blocks
#define BM 64
#define BN 64
#define GBK 64
#define LDP 72
__global__ __launch_bounds__(256) void k2_mfma(
        const __hip_bfloat16* __restrict__ A,   // pooled [3200][768]
        const __hip_bfloat16* __restrict__ Bt,  // Wt [768(n)][768(k)]
        const float* __restrict__ bias,
        const float* __restrict__ wna,          // w_news_attn [768]
        unsigned short* __restrict__ C,         // news_repr bf16 [3200][768]
        float* __restrict__ news_w) {           // [3200], pre-zeroed
    __shared__ short As[BM * LDP];
    __shared__ short Bs[BN * LDP];
    int tid = threadIdx.x;
    int wave = tid >> 6, lane = tid & 63;
    int l15 = lane & 15, l4 = lane >> 4;
    int wr = wave >> 1, wc = wave & 1;
    int row0 = blockIdx.x * BM;          // 50 row-blocks
    int col0 = blockIdx.y * BN;          // 12 col-blocks
    v4f acc[2][2] = {};

    int ra[2], ca[2];
    #pragma unroll
    for (int it = 0; it < 2; ++it) {
        int chunk = tid + it * 256;
        ra[it] = chunk >> 3; ca[it] = chunk & 7;
    }

    v8s pa[2], pb[2];
    #pragma unroll
    for (int it = 0; it < 2; ++it) {
        pa[it] = *(const v8s*)(A  + (size_t)(row0 + ra[it]) * EMBED + ca[it] * 8);
        pb[it] = *(const v8s*)(Bt + (size_t)(col0 + ra[it]) * EMBED + ca[it] * 8);
    }

    for (int s = 0; s < EMBED / GBK; ++s) {
        #pragma unroll
        for (int it = 0; it < 2; ++it) {
            *(v8s*)&As[ra[it] * LDP + ca[it] * 8] = pa[it];
            *(v8s*)&Bs[ra[it] * LDP + ca[it] * 8] = pb[it];
        }
        __syncthreads();
        if (s < EMBED / GBK - 1) {
            int k0 = (s + 1) * GBK;
            #pragma unroll
            for (int it = 0; it < 2; ++it) {
                pa[it] = *(const v8s*)(A  + (size_t)(row0 + ra[it]) * EMBED + k0 + ca[it] * 8);
                pb[it] = *(const v8s*)(Bt + (size_t)(col0 + ra[it]) * EMBED + k0 + ca[it] * 8);
            }
        }
        #pragma unroll
        for (int kk = 0; kk < 2; ++kk) {
            v8s af[2], bf_[2];
            #pragma unroll
            for (int mi = 0; mi < 2; ++mi)
                af[mi] = *(const v8s*)&As[(wr * 32 + mi * 16 + l15) * LDP + kk * 32 + l4 * 8];
            #pragma unroll
            for (int ni = 0; ni < 2; ++ni)
                bf_[ni] = *(const v8s*)&Bs[(wc * 32 + ni * 16 + l15) * LDP + kk * 32 + l4 * 8];
            #pragma unroll
            for (int mi = 0; mi < 2; ++mi)
                #pragma unroll
                for (int ni = 0; ni < 2; ++ni)
                    acc[mi][ni] = __builtin_amdgcn_mfma_f32_16x16x32_bf16(
                        af[mi], bf_[ni], acc[mi][ni], 0, 0, 0);
        }
        __syncthreads();
    }
    float bcol[2], wcol[2];
    #pragma unroll
    for (int ni = 0; ni < 2; ++ni) {
        int col = col0 + wc * 32 + ni * 16 + l15;
        bcol[ni] = bias[col]; wcol[ni] = wna[col];
    }
    #pragma unroll
    for (int mi = 0; mi < 2; ++mi) {
        #pragma unroll
        for (int r = 0; r < 4; ++r) {
            int row = row0 + wr * 32 + mi * 16 + l4 * 4 + r;
            float pr = 0.f;
            #pragma unroll
            for (int ni = 0; ni < 2; ++ni) {
                int col = col0 + wc * 32 + ni * 16 + l15;
                float tv = tanhf(acc[mi][ni][r] + bcol[ni]);
                C[(size_t)row * EMBED + col] = f2bf(tv);
                pr += tv * wcol[ni];
            }
            pr += __shfl_xor(pr, 1); pr += __shfl_xor(pr, 2);
            pr += __shfl_xor(pr, 4); pr += __shfl_xor(pr, 8);
            if (l15 == 0) atomicAdd(&news_w[row], pr);
        }
    }
}

// ---------------- K4: fused cat softmax + einsum + logits + user ----------------
__global__ __launch_bounds__(768) void k4_fused(
        const void* cmask, const unsigned short* __restrict__ nr,
        const float* __restrict__ news_w, const float* __restrict__ cat_emb,
        const float* __restrict__ w_cat, const float* __restrict__ click_emb,
        const float* __restrict__ click_w, const float* __restrict__ click_b,
        float* __restrict__ out_cat, float* __restrict__ user,
        const int* __restrict__ flagp) {
    int b = blockIdx.x, tid = threadIdx.x;
    int wave = tid >> 6, lane = tid & 63;
    int flag = *flagp;
    __shared__ float plds[HIS][20];
    __shared__ float redbuf[NUM_CAT][12];
    __shared__ float clicks[NUM_CAT];
    __shared__ int   cnts[NUM_CAT];
    __shared__ float logit[NUM_CAT];

    for (int c = wave; c < NUM_CAT; c += 12) {
        bool m = false; float v = -INFINITY;
        if (lane < HIS) {
            m = read_mask(cmask, (b * NUM_CAT + c) * HIS + lane, flag);
            if (m) v = news_w[b * HIS + lane];
        }
        unsigned long long bal = __ballot(m);
        int cnt = __popcll(bal);
        float maxv = v;
        #pragma unroll
        for (int off = 32; off; off >>= 1) maxv = fmaxf(maxv, __shfl_xor(maxv, off));
        float e = (v == -INFINITY) ? 0.f : expf(v - maxv);
        float sum = e;
        #pragma unroll
        for (int off = 32; off; off >>= 1) sum += __shfl_xor(sum, off);
        if (lane < HIS)
            plds[lane][c] = (cnt == 0 || v == -INFINITY) ? 0.f : e / sum;
        float cs = 0.f;
        if (lane < HIS) {
            const float* ce = click_emb + (size_t)cnt * CLICK_DIM;
            cs = ce[lane] * click_w[lane] + ce[lane + HIS] * click_w[lane + HIS];
        }
        #pragma unroll
        for (int off = 32; off; off >>= 1) cs += __shfl_down(cs, off);
        if (lane == 0) { cnts[c] = cnt; clicks[c] = cs + click_b[0]; }
    }
    __syncthreads();

    int col = tid;
    const unsigned short* nrb = nr + (size_t)b * HIS * EMBED;
    float acc[NUM_CAT];
    #pragma unroll
    for (int c = 0; c < NUM_CAT; ++c) acc[c] = 0.f;
    #pragma unroll 5
    for (int h = 0; h < HIS; ++h) {
        float v = bf2f(nrb[h * EMBED + col]);
        #pragma unroll
        for (int c = 0; c < NUM_CAT; ++c) acc[c] += plds[h][c] * v;
    }
    float part[NUM_CAT];
    float wv = w_cat[col];
    float* ocb = out_cat + (size_t)b * NUM_CAT * EMBED;
    #pragma unroll
    for (int c = 0; c < NUM_CAT; ++c) {
        float o = acc[c] + cat_emb[c * EMBED + col];
        acc[c] = o;
        ocb[c * EMBED + col] = o;
        part[c] = o * wv;
    }
    #pragma unroll
    for (int c = 0; c < NUM_CAT; ++c) {
        float s = part[c];
        #pragma unroll
        for (int off = 32; off; off >>= 1) s += __shfl_down(s, off);
        if (lane == 0) redbuf[c][wave] = s;
    }
    __syncthreads();
    if (tid < NUM_CAT) {
        float s = 0.f;
        #pragma unroll
        for (int w = 0; w < 12; ++w) s += redbuf[tid][w];
        logit[tid] = (cnts[tid] == 0) ? -INFINITY : (s + clicks[tid]);
    }
    __syncthreads();

    float maxv = -INFINITY;
    #pragma unroll
    for (int c = 0; c < NUM_CAT; ++c) maxv = fmaxf(maxv, logit[c]);
    float sum = 0.f;
    #pragma unroll
    for (int c = 0; c < NUM_CAT; ++c)
        sum += (logit[c] == -INFINITY) ? 0.f : expf(logit[c] - maxv);
    float u = 0.f;
    #pragma unroll
    for (int c = 0; c < NUM_CAT; ++c) {
        float w = (logit[c] == -INFINITY) ? 0.f : expf(logit[c] - maxv) / sum;
        u += w * acc[c];
    }
    user[(size_t)b * EMBED + col] = u;
}

extern "C" void kernel_launch(void* const* d_in, const int* in_sizes, int n_in,
                              void* d_out, int out_size, void* d_ws, size_t ws_size,
                              hipStream_t stream) {
    const int*   enc    = (const int*)d_in[0];
    const void*  amask  = d_in[1];
    const void*  cmask  = d_in[2];
    const float* wemb   = (const float*)d_in[3];
    const float* projw  = (const float*)d_in[4];
    const float* projb  = (const float*)d_in[5];
    const float* catemb = (const float*)d_in[6];
    const float* wna    = (const float*)d_in[7];
    const float* wca    = (const float*)d_in[8];
    const float* clemb  = (const float*)d_in[9];
    const float* clw    = (const float*)d_in[10];
    const float* clb    = (const float*)d_in[11];

    unsigned char* wsb = (unsigned char*)d_ws;
    __hip_bfloat16* pooled = (__hip_bfloat16*)(wsb + OFF_POOLED);
    __hip_bfloat16* Wt     = (__hip_bfloat16*)(wsb + OFF_WT);
    unsigned short* nr     = (unsigned short*)(wsb + OFF_NR);
    float* news_w = (float*)(wsb + OFF_NEWSW);
    int*   flag   = (int*)(wsb + OFF_FLAG);
    signed char* qtab = (signed char*)(wsb + OFF_QTAB);
    float* dscales = (float*)(wsb + OFF_DSCALE);

    float* out_cat = (float*)d_out;
    float* user    = (float*)d_out + BATCH * NUM_CAT * EMBED;

    if (ws_size >= WS_NEED) {
        kprep<<<577 + VOCAB, 256, 0, stream>>>(
            projw, Wt, (const unsigned int*)cmask, flag, wemb, qtab, dscales, news_w);
        k1c_pool<<<1600, 192, 0, stream>>>(enc, amask, (const unsigned char*)qtab,
                                           dscales, pooled, flag);
    } else {
        k0_detect<<<1, 1024, 0, stream>>>((const unsigned int*)cmask, flag, news_w);
        dim3 gt(24, 24);
        k2a_wt<<<gt, 256, 0, stream>>>(projw, Wt);
        k1_pool<<<3200, 192, 0, stream>>>(enc, amask, wemb, pooled, flag);
    }
    dim3 g2(50, 12);
    k2_mfma<<<g2, 256, 0, stream>>>(pooled, Wt, projb, wna, nr, news_w);
    k4_fused<<<BATCH, 768, 0, stream>>>(cmask, nr, news_w, catemb, wca,
                                        clemb, clw, clb, out_cat, user, flag);
}